// Round 4
// baseline (421.264 us; speedup 1.0000x reference)
//
#include <hip/hip_runtime.h>
#include <math.h>

#define NB 16

// ---------------- shapes ----------------
// x:      (16, 3,16,128,128)
// y1:     (16, 4, 8, 64, 64)   conv1 k4 s2 p1 + relu
// y2:     (16, 8, 4, 32, 32)   conv2 k4 s2 p1 + relu
// z:      (16,16, 4, 32, 32)   conv4 k3 s1 p1 + clip(0,6)
// quant:  (16,16, 4, 32, 32)   VQ
// d1:     (16, 8, 8, 64, 64)   deconv1 k4 s2 p1 + relu
// d2:     (16, 4,16,128,128)   deconv3 k4 s2 p1 + relu
// out:    (16, 3,16,128,128)   deconv4 k3 s1 p1

__device__ __forceinline__ float4 ld4(const float* p) {
  return *reinterpret_cast<const float4*>(p);
}
__device__ __forceinline__ void st4(float* p, float4 v) {
  *reinterpret_cast<float4*>(p) = v;
}

// conv1 (R4 strip, measured fast): thread = 4 co x (1 od, 1 oh, 4 ow). 512 blocks.
__global__ __launch_bounds__(256) void conv1_k(
    const float* __restrict__ x, const float* __restrict__ w,
    const float* __restrict__ bias, float* __restrict__ y) {
  int idx = blockIdx.x * 256 + threadIdx.x;
  int g  = idx & 15;
  int oh = (idx >> 4) & 63;
  int od = (idx >> 10) & 7;
  int n  = idx >> 13;
  bool gl = (g > 0), gr = (g < 15);
  float acc[4][4];
  #pragma unroll
  for (int co = 0; co < 4; co++) {
    float bv = bias[co];
    #pragma unroll
    for (int m = 0; m < 4; m++) acc[co][m] = bv;
  }
  int ih0 = 2 * oh - 1;
  #pragma unroll 1
  for (int ci = 0; ci < 3; ci++) {
    #pragma unroll 1
    for (int kd = 0; kd < 4; kd++) {
      int id = 2 * od - 1 + kd;
      bool vd = (unsigned)id < 16u;
      int idc = vd ? id : 0;
      const float* plane = x + (((n * 3 + ci) * 16 + idc) * 16384);
      #pragma unroll
      for (int kh = 0; kh < 4; kh++) {
        int ih = ih0 + kh;
        bool v = vd && ((unsigned)ih < 128u);
        int ihc = (unsigned)ih < 128u ? ih : 0;
        const float* rp = plane + ihc * 128 + 8 * g;
        float r[10];
        float4 A = ld4(rp);
        float4 B = ld4(rp + 4);
        float rl = rp[-1 * (int)gl];
        float rr = rp[gr ? 8 : 0];
        r[0] = (v && gl) ? rl : 0.0f;
        r[1] = v ? A.x : 0.0f; r[2] = v ? A.y : 0.0f;
        r[3] = v ? A.z : 0.0f; r[4] = v ? A.w : 0.0f;
        r[5] = v ? B.x : 0.0f; r[6] = v ? B.y : 0.0f;
        r[7] = v ? B.z : 0.0f; r[8] = v ? B.w : 0.0f;
        r[9] = (v && gr) ? rr : 0.0f;
        #pragma unroll
        for (int co = 0; co < 4; co++) {
          const float* wb = w + ((co * 3 + ci) * 4 + kd) * 16 + kh * 4;
          #pragma unroll
          for (int kw = 0; kw < 4; kw++) {
            float wv = wb[kw];
            #pragma unroll
            for (int m = 0; m < 4; m++)
              acc[co][m] += r[2 * m + kw] * wv;
          }
        }
      }
    }
  }
  #pragma unroll
  for (int co = 0; co < 4; co++) {
    float4 o;
    o.x = fmaxf(acc[co][0], 0.0f); o.y = fmaxf(acc[co][1], 0.0f);
    o.z = fmaxf(acc[co][2], 0.0f); o.w = fmaxf(acc[co][3], 0.0f);
    st4(y + ((n * 4 + co) * 8 + od) * 4096 + oh * 64 + 4 * g, o);
  }
}

// conv2: thread = 1 pos x 4 co. 512 blocks.
__global__ __launch_bounds__(256) void conv2_k(
    const float* __restrict__ y1, const float* __restrict__ w,
    const float* __restrict__ bias, float* __restrict__ y) {
  int idx = blockIdx.x * 256 + threadIdx.x;
  int ow = idx & 31;
  int oh = (idx >> 5) & 31;
  int od = (idx >> 10) & 3;
  int n = (idx >> 12) & 15;
  int cog = idx >> 16;
  float acc[4];
  #pragma unroll
  for (int co = 0; co < 4; co++) acc[co] = bias[cog * 4 + co];
  int id0 = 2 * od - 1, ih0 = 2 * oh - 1, iw0 = 2 * ow - 1;
  bool vh[4], vw[4];
  #pragma unroll
  for (int l = 0; l < 4; l++) {
    vh[l] = (unsigned)(ih0 + l) < 64u;
    vw[l] = (unsigned)(iw0 + l) < 64u;
  }
  #pragma unroll 1
  for (int ci = 0; ci < 4; ci++) {
    const float* ip = y1 + ((n * 4 + ci) * 8) * 4096;
    #pragma unroll
    for (int kd = 0; kd < 4; kd++) {
      int id = id0 + kd;
      bool vd = (unsigned)id < 8u;
      const float* pp = ip + id * 4096;
      float p[4][4];
      #pragma unroll
      for (int kh = 0; kh < 4; kh++)
        #pragma unroll
        for (int kw = 0; kw < 4; kw++)
          p[kh][kw] = (vd && vh[kh] && vw[kw]) ? pp[(ih0 + kh) * 64 + (iw0 + kw)] : 0.0f;
      #pragma unroll
      for (int co = 0; co < 4; co++) {
        const float* wp = w + (((cog * 4 + co) * 4 + ci) * 4 + kd) * 16;
        #pragma unroll
        for (int kh = 0; kh < 4; kh++)
          #pragma unroll
          for (int kw = 0; kw < 4; kw++)
            acc[co] += p[kh][kw] * wp[kh * 4 + kw];
      }
    }
  }
  #pragma unroll
  for (int co = 0; co < 4; co++)
    y[((n * 8 + cog * 4 + co) * 4 + od) * 1024 + oh * 32 + ow] = fmaxf(acc[co], 0.0f);
}

// conv4: thread = 1 pos x 4 co. 1024 blocks.
__global__ __launch_bounds__(256) void conv4_k(
    const float* __restrict__ y2, const float* __restrict__ w,
    const float* __restrict__ bias, float* __restrict__ z) {
  int idx = blockIdx.x * 256 + threadIdx.x;
  int ow = idx & 31;
  int oh = (idx >> 5) & 31;
  int od = (idx >> 10) & 3;
  int n = (idx >> 12) & 15;
  int cog = idx >> 16;
  float acc[4];
  #pragma unroll
  for (int co = 0; co < 4; co++) acc[co] = bias[cog * 4 + co];
  bool vh[3], vw[3];
  #pragma unroll
  for (int l = 0; l < 3; l++) {
    vh[l] = (unsigned)(oh - 1 + l) < 32u;
    vw[l] = (unsigned)(ow - 1 + l) < 32u;
  }
  #pragma unroll 1
  for (int ci = 0; ci < 8; ci++) {
    const float* ip = y2 + ((n * 8 + ci) * 4) * 1024;
    #pragma unroll
    for (int kd = 0; kd < 3; kd++) {
      int id = od - 1 + kd;
      bool vd = (unsigned)id < 4u;
      const float* pp = ip + id * 1024;
      float p[3][3];
      #pragma unroll
      for (int kh = 0; kh < 3; kh++)
        #pragma unroll
        for (int kw = 0; kw < 3; kw++)
          p[kh][kw] = (vd && vh[kh] && vw[kw]) ? pp[(oh - 1 + kh) * 32 + (ow - 1 + kw)] : 0.0f;
      #pragma unroll
      for (int co = 0; co < 4; co++) {
        const float* wp = w + (((cog * 4 + co) * 8 + ci) * 3 + kd) * 9;
        #pragma unroll
        for (int kh = 0; kh < 3; kh++)
          #pragma unroll
          for (int kw = 0; kw < 3; kw++)
            acc[co] += p[kh][kw] * wp[kh * 3 + kw];
      }
    }
  }
  #pragma unroll
  for (int co = 0; co < 4; co++)
    z[((n * 16 + cog * 4 + co) * 4 + od) * 1024 + oh * 32 + ow] =
        fminf(fmaxf(acc[co], 0.0f), 6.0f);
}

// VQ (unchanged)
__global__ __launch_bounds__(256) void vq_k(
    const float* __restrict__ z, const float* __restrict__ emb,
    float* __restrict__ quant, float* __restrict__ codes_out,
    float* __restrict__ stats) {
  __shared__ float se[32 * 16];
  __shared__ float se2[32];
  __shared__ float shist[32];
  __shared__ float swred[4];
  int tid = threadIdx.x;
  for (int i = tid; i < 512; i += 256) {
    int r = i >> 4;
    float v = emb[i];
    if (r == 0) v = 0.0f;
    else if (r == 1) v = 6.0f;
    se[i] = v;
  }
  if (tid < 32) shist[tid] = 0.0f;
  __syncthreads();
  if (tid < 32) {
    float s = 0.0f;
    #pragma unroll
    for (int d = 0; d < 16; d++) { float v = se[tid * 16 + d]; s += v * v; }
    se2[tid] = s;
  }
  __syncthreads();

  int idx = blockIdx.x * 256 + tid;
  float lsum = 0.0f;
  {
    int w_ = idx & 31; int t = idx >> 5;
    int h_ = t & 31; t >>= 5;
    int d_ = t & 3;  int b_ = t >> 2;
    const float* zp = z + b_ * 65536 + d_ * 1024 + h_ * 32 + w_;
    float f[16];
    float f2 = 0.0f;
    #pragma unroll
    for (int c = 0; c < 16; c++) { float v = zp[c * 4096]; f[c] = v; f2 += v * v; }
    float best = 1e30f; int bi = 0;
    for (int e = 0; e < 32; e++) {
      float dot = 0.0f;
      #pragma unroll
      for (int c = 0; c < 16; c++) dot += f[c] * se[e * 16 + c];
      float d2 = f2 - 2.0f * dot + se2[e];
      if (d2 < best) { best = d2; bi = e; }
    }
    float* qp = quant + b_ * 65536 + d_ * 1024 + h_ * 32 + w_;
    #pragma unroll
    for (int c = 0; c < 16; c++) {
      float q = se[bi * 16 + c];
      qp[c * 4096] = q;
      float df = q - f[c];
      lsum += df * df;
    }
    codes_out[idx] = (float)bi;
    atomicAdd(&shist[bi], 1.0f);
  }
  for (int o = 32; o; o >>= 1) lsum += __shfl_down(lsum, o);
  if ((tid & 63) == 0) swred[tid >> 6] = lsum;
  __syncthreads();
  if (tid == 0) atomicAdd(&stats[0], swred[0] + swred[1] + swred[2] + swred[3]);
  if (tid < 32) {
    float h = shist[tid];
    if (h != 0.0f) atomicAdd(&stats[1 + tid], h);
  }
}

__global__ void init_stats_k(float* __restrict__ stats) {
  int tid = threadIdx.x;
  if (tid < 33) stats[tid] = 0.0f;
}

__global__ void fin_k(const float* __restrict__ stats,
                      const float* __restrict__ cluster_size,
                      float* __restrict__ out_loss, float* __restrict__ out_perp,
                      float* __restrict__ out_used) {
  int tid = threadIdx.x;
  float v = 0.0f;
  float used = 0.0f;
  if (tid < 32) {
    float p = stats[1 + tid] * (1.0f / 65536.0f);
    v = p * logf(p + 1e-10f);
    used = (cluster_size[tid] > 1e-5f) ? 1.0f : 0.0f;
  }
  for (int o = 16; o; o >>= 1) { v += __shfl_down(v, o); used += __shfl_down(used, o); }
  if (tid == 0) {
    *out_perp = expf(-v);
    *out_used = used * (1.0f / 32.0f);
    *out_loss = 0.25f * stats[0] * (1.0f / 1048576.0f);
  }
}

// ============ deconv1 v3 (strip, unchanged) ============
// quant (16,16,4,32,32) -> d1 (16,8,8,64,64), k4 s2 p1.
// Grid: cog(2) x ph(2) x od(8) x n(16) = 512 blocks; block = g(8) x bl(32).
__global__ __launch_bounds__(256) void deconv1_k(
    const float* __restrict__ q, const float* __restrict__ w,
    const float* __restrict__ bias, float* __restrict__ d1) {
  int bid = blockIdx.x;
  int cog = bid & 1;
  int ph  = (bid >> 1) & 1;
  int od  = (bid >> 2) & 7;
  int n   = bid >> 5;
  int tid = threadIdx.x;
  int g   = tid & 7;     // ow strip 8g..8g+7; input cols 4g-1..4g+4
  int bl  = tid >> 3;    // 0..31; oh = 2*bl + ph
  bool glf = (g > 0), grf = (g < 7);

  int kd0 = (od + 1) & 1;
  int idtop = (od + 1 - kd0) >> 1;  // id = idtop - jd, kd = kd0 + 2*jd
  int kh0 = (ph + 1) & 1;
  int ihtop = bl + ph;              // ih = ihtop - jh, kh = kh0 + 2*jh

  float acc[4][8];
  #pragma unroll
  for (int co = 0; co < 4; co++) {
    float bv = bias[cog * 4 + co];
    #pragma unroll
    for (int m = 0; m < 8; m++) acc[co][m] = bv;
  }

  #pragma unroll 1
  for (int ci = 0; ci < 16; ci++) {
    const float* ip = q + ((n * 16 + ci) * 4) * 1024;
    #pragma unroll
    for (int jd = 0; jd < 2; jd++) {
      int id = idtop - jd;
      bool vd = (unsigned)id < 4u;
      int idc = vd ? id : 0;
      const float* plane = ip + idc * 1024;
      #pragma unroll
      for (int jh = 0; jh < 2; jh++) {
        int ih = ihtop - jh;
        bool v = vd && ((unsigned)ih < 32u);
        int ihc = (unsigned)ih < 32u ? ih : 0;
        const float* rp = plane + ihc * 32 + 4 * g;
        float r[6];
        float4 A = ld4(rp);
        float rl = rp[-1 * (int)glf];
        float rr = rp[grf ? 4 : 0];
        r[0] = (v && glf) ? rl : 0.0f;
        r[1] = v ? A.x : 0.0f; r[2] = v ? A.y : 0.0f;
        r[3] = v ? A.z : 0.0f; r[4] = v ? A.w : 0.0f;
        r[5] = (v && grf) ? rr : 0.0f;
        int kd = kd0 + 2 * jd;
        int kh = kh0 + 2 * jh;
        #pragma unroll
        for (int co = 0; co < 4; co++) {
          const float* wb = w + ((ci * 8 + cog * 4 + co) * 4 + kd) * 16 + kh * 4;
          #pragma unroll
          for (int jw = 0; jw < 2; jw++) {
            float w_ev = wb[1 + 2 * jw];  // kw for even ow (pw=0)
            float w_od = wb[2 * jw];      // kw for odd  ow (pw=1)
            #pragma unroll
            for (int ii = 0; ii < 4; ii++) {
              acc[co][2 * ii]     += r[ii + 1 - jw] * w_ev;
              acc[co][2 * ii + 1] += r[ii + 2 - jw] * w_od;
            }
          }
        }
      }
    }
  }
  int oh = 2 * bl + ph;
  #pragma unroll
  for (int co = 0; co < 4; co++) {
    float* op = d1 + ((n * 8 + cog * 4 + co) * 8 + od) * 4096 + oh * 64 + 8 * g;
    float4 lo, hi;
    lo.x = fmaxf(acc[co][0], 0.0f); lo.y = fmaxf(acc[co][1], 0.0f);
    lo.z = fmaxf(acc[co][2], 0.0f); lo.w = fmaxf(acc[co][3], 0.0f);
    hi.x = fmaxf(acc[co][4], 0.0f); hi.y = fmaxf(acc[co][5], 0.0f);
    hi.z = fmaxf(acc[co][6], 0.0f); hi.w = fmaxf(acc[co][7], 0.0f);
    st4(op, lo); st4(op + 4, hi);
  }
}

// ============ deconv3 v3 (strip — measured improvement, kept) ============
// d1 (16,8,8,64,64) -> d2 (16,4,16,128,128), k4 s2 p1 + relu.
// Grid: ph(2) x blh(4) x od(16) x n(16) = 2048 blocks; block = g(16) x bl(16).
__global__ __launch_bounds__(256) void deconv3_k(
    const float* __restrict__ d1, const float* __restrict__ w,
    const float* __restrict__ bias, float* __restrict__ d2) {
  int bid = blockIdx.x;
  int ph  = bid & 1;
  int blh = (bid >> 1) & 3;
  int od  = (bid >> 3) & 15;
  int n   = bid >> 7;
  int tid = threadIdx.x;
  int g   = tid & 15;       // ow strip 8g..8g+7; input cols 4g-1..4g+4
  int bl  = tid >> 4;       // 0..15
  int BL  = blh * 16 + bl;  // oh = 2*BL + ph
  bool glf = (g > 0), grf = (g < 15);

  int kd0 = (od + 1) & 1;
  int idtop = (od + 1 - kd0) >> 1;  // id = idtop - jd, kd = kd0 + 2*jd
  int kh0 = (ph + 1) & 1;
  int ihtop = BL + ph;              // ih = ihtop - jh, kh = kh0 + 2*jh

  float acc[4][8];
  #pragma unroll
  for (int co = 0; co < 4; co++) {
    float bv = bias[co];
    #pragma unroll
    for (int m = 0; m < 8; m++) acc[co][m] = bv;
  }

  #pragma unroll 1
  for (int ci = 0; ci < 8; ci++) {
    const float* ip = d1 + ((n * 8 + ci) * 8) * 4096;
    #pragma unroll
    for (int jd = 0; jd < 2; jd++) {
      int id = idtop - jd;
      bool vd = (unsigned)id < 8u;
      int idc = vd ? id : 0;
      const float* plane = ip + idc * 4096;
      #pragma unroll
      for (int jh = 0; jh < 2; jh++) {
        int ih = ihtop - jh;
        bool v = vd && ((unsigned)ih < 64u);
        int ihc = (unsigned)ih < 64u ? ih : 0;
        const float* rp = plane + ihc * 64 + 4 * g;
        float r[6];
        float4 A = ld4(rp);
        float rl = rp[-1 * (int)glf];
        float rr = rp[grf ? 4 : 0];
        r[0] = (v && glf) ? rl : 0.0f;
        r[1] = v ? A.x : 0.0f; r[2] = v ? A.y : 0.0f;
        r[3] = v ? A.z : 0.0f; r[4] = v ? A.w : 0.0f;
        r[5] = (v && grf) ? rr : 0.0f;
        int kd = kd0 + 2 * jd;
        int kh = kh0 + 2 * jh;
        #pragma unroll
        for (int co = 0; co < 4; co++) {
          const float* wb = w + ((ci * 4 + co) * 4 + kd) * 16 + kh * 4;
          #pragma unroll
          for (int jw = 0; jw < 2; jw++) {
            float w_ev = wb[1 + 2 * jw];  // kw for even ow (pw=0)
            float w_od = wb[2 * jw];      // kw for odd  ow (pw=1)
            #pragma unroll
            for (int ii = 0; ii < 4; ii++) {
              acc[co][2 * ii]     += r[ii + 1 - jw] * w_ev;
              acc[co][2 * ii + 1] += r[ii + 2 - jw] * w_od;
            }
          }
        }
      }
    }
  }
  int oh = 2 * BL + ph;
  #pragma unroll
  for (int co = 0; co < 4; co++) {
    float* op = d2 + ((n * 4 + co) * 16 + od) * 16384 + oh * 128 + 8 * g;
    float4 lo, hi;
    lo.x = fmaxf(acc[co][0], 0.0f); lo.y = fmaxf(acc[co][1], 0.0f);
    lo.z = fmaxf(acc[co][2], 0.0f); lo.w = fmaxf(acc[co][3], 0.0f);
    hi.x = fmaxf(acc[co][4], 0.0f); hi.y = fmaxf(acc[co][5], 0.0f);
    hi.z = fmaxf(acc[co][6], 0.0f); hi.w = fmaxf(acc[co][7], 0.0f);
    st4(op, lo); st4(op + 4, hi);
  }
}

// ============ deconv4 v3 (LDS-staged tile) ============
// d2 (16,4,16,128,128) -> out (16,3,16,128,128): stride-1 3x3x3 conv with
// flipped weights: out[o] += in[o-1+k]*w_orig[2-k] per dim (verified in R0 strip).
// Grid: ohg(4) x od(16) x n(16) = 1024 blocks; block 256 = oh_local(32) x owg(8).
// Per phase (kd,ci): stage one 34x130 input plane into LDS (coalesced, bounds
// resolved at stage time), then each thread computes a 16-wide ow strip x 3 co
// from LDS. Row stride 140 floats: 16-col strips -> 2-way bank alias (free).
#define D4_STRIDE 140
#define D4_ELEMS (34 * D4_STRIDE)   // 4760
__global__ __launch_bounds__(256) void deconv4_k(
    const float* __restrict__ d2, const float* __restrict__ w,
    const float* __restrict__ bias, float* __restrict__ out) {
  __shared__ float sh[D4_ELEMS];
  int bid = blockIdx.x;
  int ohg = bid & 3;
  int od  = (bid >> 2) & 15;
  int n   = bid >> 6;
  int tid = threadIdx.x;
  int owg = tid & 7;          // ow strip 16*owg .. 16*owg+15
  int ohl = tid >> 3;         // 0..31
  int ow0 = 16 * owg;
  int oh0m1 = 32 * ohg - 1;   // global row of LDS row 0

  float acc[3][16];
  #pragma unroll
  for (int co = 0; co < 3; co++) {
    float bv = bias[co];
    #pragma unroll
    for (int m = 0; m < 16; m++) acc[co][m] = bv;
  }

  #pragma unroll 1
  for (int kd = 0; kd < 3; kd++) {
    int id = od - 1 + kd;
    if ((unsigned)id >= 16u) continue;  // block-uniform branch
    #pragma unroll 1
    for (int ci = 0; ci < 4; ci++) {
      const float* gp = d2 + ((n * 4 + ci) * 16 + id) * 16384;
      __syncthreads();  // previous compute done before overwrite
      #pragma unroll 1
      for (int k = 0; k < 19; k++) {
        int e = tid + k * 256;
        if (e < D4_ELEMS) {
          int row = e / D4_STRIDE;
          int lcol = e - row * D4_STRIDE;
          int ih = oh0m1 + row;
          int iw = lcol - 1;
          float v = 0.0f;
          if (lcol < 130 && (unsigned)ih < 128u && (unsigned)iw < 128u)
            v = gp[ih * 128 + iw];
          sh[e] = v;
        }
      }
      __syncthreads();
      #pragma unroll
      for (int kh = 0; kh < 3; kh++) {
        const float* rp = &sh[(ohl + kh) * D4_STRIDE + ow0];
        float r[18];
        float4 A = ld4(rp);
        float4 B = ld4(rp + 4);
        float4 C = ld4(rp + 8);
        float4 D = ld4(rp + 12);
        r[0] = A.x;  r[1] = A.y;  r[2] = A.z;  r[3] = A.w;
        r[4] = B.x;  r[5] = B.y;  r[6] = B.z;  r[7] = B.w;
        r[8] = C.x;  r[9] = C.y;  r[10] = C.z; r[11] = C.w;
        r[12] = D.x; r[13] = D.y; r[14] = D.z; r[15] = D.w;
        r[16] = rp[16]; r[17] = rp[17];
        #pragma unroll
        for (int co = 0; co < 3; co++) {
          // flipped weight base: w[(ci*3+co)*27 + (2-kd)*9 + (2-kh)*3 + (2-kw)]
          const float* wb = w + (ci * 3 + co) * 27 + (2 - kd) * 9 + (2 - kh) * 3;
          #pragma unroll
          for (int kw = 0; kw < 3; kw++) {
            float wv = wb[2 - kw];
            #pragma unroll
            for (int m = 0; m < 16; m++)
              acc[co][m] += r[m + kw] * wv;
          }
        }
      }
    }
  }

  int oh = 32 * ohg + ohl;
  #pragma unroll
  for (int co = 0; co < 3; co++) {
    float* op = out + ((n * 3 + co) * 16 + od) * 16384 + oh * 128 + ow0;
    #pragma unroll
    for (int q = 0; q < 4; q++) {
      float4 o;
      o.x = acc[co][4 * q]; o.y = acc[co][4 * q + 1];
      o.z = acc[co][4 * q + 2]; o.w = acc[co][4 * q + 3];
      st4(op + 4 * q, o);
    }
  }
}

extern "C" void kernel_launch(void* const* d_in, const int* in_sizes, int n_in,
                              void* d_out, int out_size, void* d_ws, size_t ws_size,
                              hipStream_t stream) {
  const float* x      = (const float*)d_in[0];
  const float* enc_w1 = (const float*)d_in[2];
  const float* enc_b1 = (const float*)d_in[3];
  const float* enc_w2 = (const float*)d_in[4];
  const float* enc_b2 = (const float*)d_in[5];
  const float* enc_w4 = (const float*)d_in[6];
  const float* enc_b4 = (const float*)d_in[7];
  const float* dec_w1 = (const float*)d_in[8];
  const float* dec_b1 = (const float*)d_in[9];
  const float* dec_w3 = (const float*)d_in[10];
  const float* dec_b3 = (const float*)d_in[11];
  const float* dec_w4 = (const float*)d_in[12];
  const float* dec_b4 = (const float*)d_in[13];
  const float* emb    = (const float*)d_in[14];
  const float* csize  = (const float*)d_in[15];

  float* ws = (float*)d_ws;
  float* stats = ws;                      // 64
  float* quant = ws + 64;                 // 1,048,576
  float* z     = quant + 1048576;         // 1,048,576
  float* y2    = z + 1048576;             // 524,288
  float* y1    = y2 + 524288;             // 2,097,152 (dead after conv2)
  float* d1    = z;                       // 4,194,304 (reuses z/y2/y1)
  float* d2    = ws + 64 + 1048576 + 4194304;  // 16,777,216

  float* out   = (float*)d_out;                        // 12,582,912
  float* out_loss  = out + 12582912;
  float* out_codes = out_loss + 1;                     // 65,536
  float* out_perp  = out_codes + 65536;
  float* out_used  = out_perp + 1;

  init_stats_k<<<1, 64, 0, stream>>>(stats);

  conv1_k<<<512, 256, 0, stream>>>(x, enc_w1, enc_b1, y1);
  conv2_k<<<512, 256, 0, stream>>>(y1, enc_w2, enc_b2, y2);
  conv4_k<<<1024, 256, 0, stream>>>(y2, enc_w4, enc_b4, z);

  vq_k<<<256, 256, 0, stream>>>(z, emb, quant, out_codes, stats);
  fin_k<<<1, 64, 0, stream>>>(stats, csize, out_loss, out_perp, out_used);

  deconv1_k<<<512, 256, 0, stream>>>(quant, dec_w1, dec_b1, d1);
  deconv3_k<<<2048, 256, 0, stream>>>(d1, dec_w3, dec_b3, d2);
  deconv4_k<<<1024, 256, 0, stream>>>(d2, dec_w4, dec_b4, out);
}

// Round 5
// 402.668 us; speedup vs baseline: 1.0462x; 1.0462x over previous
//
#include <hip/hip_runtime.h>
#include <math.h>

#define NB 16

// ---------------- shapes ----------------
// x:      (16, 3,16,128,128)
// y1:     (16, 4, 8, 64, 64)   conv1 k4 s2 p1 + relu
// y2:     (16, 8, 4, 32, 32)   conv2 k4 s2 p1 + relu
// z:      (in-register)        conv4 k3 s1 p1 + clip(0,6), fused with VQ
// quant:  (16,16, 4, 32, 32)   VQ
// d1:     (16, 8, 8, 64, 64)   deconv1 k4 s2 p1 + relu
// d2:     (16, 4,16,128,128)   deconv3 k4 s2 p1 + relu
// out:    (16, 3,16,128,128)   deconv4 k3 s1 p1

__device__ __forceinline__ float4 ld4(const float* p) {
  return *reinterpret_cast<const float4*>(p);
}
__device__ __forceinline__ void st4(float* p, float4 v) {
  *reinterpret_cast<float4*>(p) = v;
}

// conv1 (R4 strip, measured fast): thread = 4 co x (1 od, 1 oh, 4 ow). 512 blocks.
__global__ __launch_bounds__(256) void conv1_k(
    const float* __restrict__ x, const float* __restrict__ w,
    const float* __restrict__ bias, float* __restrict__ y) {
  int idx = blockIdx.x * 256 + threadIdx.x;
  int g  = idx & 15;
  int oh = (idx >> 4) & 63;
  int od = (idx >> 10) & 7;
  int n  = idx >> 13;
  bool gl = (g > 0), gr = (g < 15);
  float acc[4][4];
  #pragma unroll
  for (int co = 0; co < 4; co++) {
    float bv = bias[co];
    #pragma unroll
    for (int m = 0; m < 4; m++) acc[co][m] = bv;
  }
  int ih0 = 2 * oh - 1;
  #pragma unroll 1
  for (int ci = 0; ci < 3; ci++) {
    #pragma unroll 1
    for (int kd = 0; kd < 4; kd++) {
      int id = 2 * od - 1 + kd;
      bool vd = (unsigned)id < 16u;
      int idc = vd ? id : 0;
      const float* plane = x + (((n * 3 + ci) * 16 + idc) * 16384);
      #pragma unroll
      for (int kh = 0; kh < 4; kh++) {
        int ih = ih0 + kh;
        bool v = vd && ((unsigned)ih < 128u);
        int ihc = (unsigned)ih < 128u ? ih : 0;
        const float* rp = plane + ihc * 128 + 8 * g;
        float r[10];
        float4 A = ld4(rp);
        float4 B = ld4(rp + 4);
        float rl = rp[-1 * (int)gl];
        float rr = rp[gr ? 8 : 0];
        r[0] = (v && gl) ? rl : 0.0f;
        r[1] = v ? A.x : 0.0f; r[2] = v ? A.y : 0.0f;
        r[3] = v ? A.z : 0.0f; r[4] = v ? A.w : 0.0f;
        r[5] = v ? B.x : 0.0f; r[6] = v ? B.y : 0.0f;
        r[7] = v ? B.z : 0.0f; r[8] = v ? B.w : 0.0f;
        r[9] = (v && gr) ? rr : 0.0f;
        #pragma unroll
        for (int co = 0; co < 4; co++) {
          const float* wb = w + ((co * 3 + ci) * 4 + kd) * 16 + kh * 4;
          #pragma unroll
          for (int kw = 0; kw < 4; kw++) {
            float wv = wb[kw];
            #pragma unroll
            for (int m = 0; m < 4; m++)
              acc[co][m] += r[2 * m + kw] * wv;
          }
        }
      }
    }
  }
  #pragma unroll
  for (int co = 0; co < 4; co++) {
    float4 o;
    o.x = fmaxf(acc[co][0], 0.0f); o.y = fmaxf(acc[co][1], 0.0f);
    o.z = fmaxf(acc[co][2], 0.0f); o.w = fmaxf(acc[co][3], 0.0f);
    st4(y + ((n * 4 + co) * 8 + od) * 4096 + oh * 64 + 4 * g, o);
  }
}

// conv2: thread = 1 pos x 4 co. 512 blocks.
__global__ __launch_bounds__(256) void conv2_k(
    const float* __restrict__ y1, const float* __restrict__ w,
    const float* __restrict__ bias, float* __restrict__ y) {
  int idx = blockIdx.x * 256 + threadIdx.x;
  int ow = idx & 31;
  int oh = (idx >> 5) & 31;
  int od = (idx >> 10) & 3;
  int n = (idx >> 12) & 15;
  int cog = idx >> 16;
  float acc[4];
  #pragma unroll
  for (int co = 0; co < 4; co++) acc[co] = bias[cog * 4 + co];
  int id0 = 2 * od - 1, ih0 = 2 * oh - 1, iw0 = 2 * ow - 1;
  bool vh[4], vw[4];
  #pragma unroll
  for (int l = 0; l < 4; l++) {
    vh[l] = (unsigned)(ih0 + l) < 64u;
    vw[l] = (unsigned)(iw0 + l) < 64u;
  }
  #pragma unroll 1
  for (int ci = 0; ci < 4; ci++) {
    const float* ip = y1 + ((n * 4 + ci) * 8) * 4096;
    #pragma unroll
    for (int kd = 0; kd < 4; kd++) {
      int id = id0 + kd;
      bool vd = (unsigned)id < 8u;
      const float* pp = ip + id * 4096;
      float p[4][4];
      #pragma unroll
      for (int kh = 0; kh < 4; kh++)
        #pragma unroll
        for (int kw = 0; kw < 4; kw++)
          p[kh][kw] = (vd && vh[kh] && vw[kw]) ? pp[(ih0 + kh) * 64 + (iw0 + kw)] : 0.0f;
      #pragma unroll
      for (int co = 0; co < 4; co++) {
        const float* wp = w + (((cog * 4 + co) * 4 + ci) * 4 + kd) * 16;
        #pragma unroll
        for (int kh = 0; kh < 4; kh++)
          #pragma unroll
          for (int kw = 0; kw < 4; kw++)
            acc[co] += p[kh][kw] * wp[kh * 4 + kw];
      }
    }
  }
  #pragma unroll
  for (int co = 0; co < 4; co++)
    y[((n * 8 + cog * 4 + co) * 4 + od) * 1024 + oh * 32 + ow] = fmaxf(acc[co], 0.0f);
}

// ============ conv4 + VQ fused ============
// Thread = 1 pos x ALL 16 co; conv4 k3 s1 p1 + clip(0,6), then VQ in-register.
// Grid: 256 blocks x 256 (65536 positions). z never touches memory.
__global__ __launch_bounds__(256) void conv4vq_k(
    const float* __restrict__ y2, const float* __restrict__ w,
    const float* __restrict__ bias, const float* __restrict__ emb,
    float* __restrict__ quant, float* __restrict__ codes_out,
    float* __restrict__ stats) {
  __shared__ float se[32 * 16];
  __shared__ float se2[32];
  __shared__ float shist[32];
  __shared__ float swred[4];
  int tid = threadIdx.x;
  for (int i = tid; i < 512; i += 256) {
    int r = i >> 4;
    float v = emb[i];
    if (r == 0) v = 0.0f;
    else if (r == 1) v = 6.0f;
    se[i] = v;
  }
  if (tid < 32) shist[tid] = 0.0f;
  __syncthreads();
  if (tid < 32) {
    float s = 0.0f;
    #pragma unroll
    for (int d = 0; d < 16; d++) { float v = se[tid * 16 + d]; s += v * v; }
    se2[tid] = s;
  }
  __syncthreads();

  int idx = blockIdx.x * 256 + tid;
  int ow = idx & 31;
  int oh = (idx >> 5) & 31;
  int od = (idx >> 10) & 3;
  int n  = idx >> 12;

  // ---- conv4 (all 16 channels) ----
  float acc[16];
  #pragma unroll
  for (int co = 0; co < 16; co++) acc[co] = bias[co];
  bool vh[3], vw[3];
  #pragma unroll
  for (int l = 0; l < 3; l++) {
    vh[l] = (unsigned)(oh - 1 + l) < 32u;
    vw[l] = (unsigned)(ow - 1 + l) < 32u;
  }
  #pragma unroll 1
  for (int ci = 0; ci < 8; ci++) {
    const float* ip = y2 + ((n * 8 + ci) * 4) * 1024;
    #pragma unroll
    for (int kd = 0; kd < 3; kd++) {
      int id = od - 1 + kd;
      bool vd = (unsigned)id < 4u;
      const float* pp = ip + id * 1024;
      float p[3][3];
      #pragma unroll
      for (int kh = 0; kh < 3; kh++)
        #pragma unroll
        for (int kw = 0; kw < 3; kw++)
          p[kh][kw] = (vd && vh[kh] && vw[kw]) ? pp[(oh - 1 + kh) * 32 + (ow - 1 + kw)] : 0.0f;
      #pragma unroll
      for (int co = 0; co < 16; co++) {
        const float* wp = w + ((co * 8 + ci) * 3 + kd) * 9;
        #pragma unroll
        for (int kh = 0; kh < 3; kh++)
          #pragma unroll
          for (int kw = 0; kw < 3; kw++)
            acc[co] += p[kh][kw] * wp[kh * 3 + kw];
      }
    }
  }
  // clip(0,6) -> f[], f2
  float f2 = 0.0f;
  #pragma unroll
  for (int c = 0; c < 16; c++) {
    float v = fminf(fmaxf(acc[c], 0.0f), 6.0f);
    acc[c] = v;
    f2 += v * v;
  }

  // ---- VQ (verbatim from verified vq_k, f[] in registers) ----
  float lsum = 0.0f;
  {
    float best = 1e30f; int bi = 0;
    for (int e = 0; e < 32; e++) {
      float dot = 0.0f;
      #pragma unroll
      for (int c = 0; c < 16; c++) dot += acc[c] * se[e * 16 + c];
      float d2 = f2 - 2.0f * dot + se2[e];
      if (d2 < best) { best = d2; bi = e; }
    }
    float* qp = quant + n * 65536 + od * 1024 + oh * 32 + ow;
    #pragma unroll
    for (int c = 0; c < 16; c++) {
      float q = se[bi * 16 + c];
      qp[c * 4096] = q;
      float df = q - acc[c];
      lsum += df * df;
    }
    codes_out[idx] = (float)bi;
    atomicAdd(&shist[bi], 1.0f);
  }
  for (int o = 32; o; o >>= 1) lsum += __shfl_down(lsum, o);
  if ((tid & 63) == 0) swred[tid >> 6] = lsum;
  __syncthreads();
  if (tid == 0) atomicAdd(&stats[0], swred[0] + swred[1] + swred[2] + swred[3]);
  if (tid < 32) {
    float h = shist[tid];
    if (h != 0.0f) atomicAdd(&stats[1 + tid], h);
  }
}

__global__ void init_stats_k(float* __restrict__ stats) {
  int tid = threadIdx.x;
  if (tid < 33) stats[tid] = 0.0f;
}

__global__ void fin_k(const float* __restrict__ stats,
                      const float* __restrict__ cluster_size,
                      float* __restrict__ out_loss, float* __restrict__ out_perp,
                      float* __restrict__ out_used) {
  int tid = threadIdx.x;
  float v = 0.0f;
  float used = 0.0f;
  if (tid < 32) {
    float p = stats[1 + tid] * (1.0f / 65536.0f);
    v = p * logf(p + 1e-10f);
    used = (cluster_size[tid] > 1e-5f) ? 1.0f : 0.0f;
  }
  for (int o = 16; o; o >>= 1) { v += __shfl_down(v, o); used += __shfl_down(used, o); }
  if (tid == 0) {
    *out_perp = expf(-v);
    *out_used = used * (1.0f / 32.0f);
    *out_loss = 0.25f * stats[0] * (1.0f / 1048576.0f);
  }
}

// ============ deconv1 v3 (strip, unchanged) ============
// quant (16,16,4,32,32) -> d1 (16,8,8,64,64), k4 s2 p1.
// Grid: cog(2) x ph(2) x od(8) x n(16) = 512 blocks; block = g(8) x bl(32).
__global__ __launch_bounds__(256) void deconv1_k(
    const float* __restrict__ q, const float* __restrict__ w,
    const float* __restrict__ bias, float* __restrict__ d1) {
  int bid = blockIdx.x;
  int cog = bid & 1;
  int ph  = (bid >> 1) & 1;
  int od  = (bid >> 2) & 7;
  int n   = bid >> 5;
  int tid = threadIdx.x;
  int g   = tid & 7;     // ow strip 8g..8g+7; input cols 4g-1..4g+4
  int bl  = tid >> 3;    // 0..31; oh = 2*bl + ph
  bool glf = (g > 0), grf = (g < 7);

  int kd0 = (od + 1) & 1;
  int idtop = (od + 1 - kd0) >> 1;  // id = idtop - jd, kd = kd0 + 2*jd
  int kh0 = (ph + 1) & 1;
  int ihtop = bl + ph;              // ih = ihtop - jh, kh = kh0 + 2*jh

  float acc[4][8];
  #pragma unroll
  for (int co = 0; co < 4; co++) {
    float bv = bias[cog * 4 + co];
    #pragma unroll
    for (int m = 0; m < 8; m++) acc[co][m] = bv;
  }

  #pragma unroll 1
  for (int ci = 0; ci < 16; ci++) {
    const float* ip = q + ((n * 16 + ci) * 4) * 1024;
    #pragma unroll
    for (int jd = 0; jd < 2; jd++) {
      int id = idtop - jd;
      bool vd = (unsigned)id < 4u;
      int idc = vd ? id : 0;
      const float* plane = ip + idc * 1024;
      #pragma unroll
      for (int jh = 0; jh < 2; jh++) {
        int ih = ihtop - jh;
        bool v = vd && ((unsigned)ih < 32u);
        int ihc = (unsigned)ih < 32u ? ih : 0;
        const float* rp = plane + ihc * 32 + 4 * g;
        float r[6];
        float4 A = ld4(rp);
        float rl = rp[-1 * (int)glf];
        float rr = rp[grf ? 4 : 0];
        r[0] = (v && glf) ? rl : 0.0f;
        r[1] = v ? A.x : 0.0f; r[2] = v ? A.y : 0.0f;
        r[3] = v ? A.z : 0.0f; r[4] = v ? A.w : 0.0f;
        r[5] = (v && grf) ? rr : 0.0f;
        int kd = kd0 + 2 * jd;
        int kh = kh0 + 2 * jh;
        #pragma unroll
        for (int co = 0; co < 4; co++) {
          const float* wb = w + ((ci * 8 + cog * 4 + co) * 4 + kd) * 16 + kh * 4;
          #pragma unroll
          for (int jw = 0; jw < 2; jw++) {
            float w_ev = wb[1 + 2 * jw];  // kw for even ow (pw=0)
            float w_od = wb[2 * jw];      // kw for odd  ow (pw=1)
            #pragma unroll
            for (int ii = 0; ii < 4; ii++) {
              acc[co][2 * ii]     += r[ii + 1 - jw] * w_ev;
              acc[co][2 * ii + 1] += r[ii + 2 - jw] * w_od;
            }
          }
        }
      }
    }
  }
  int oh = 2 * bl + ph;
  #pragma unroll
  for (int co = 0; co < 4; co++) {
    float* op = d1 + ((n * 8 + cog * 4 + co) * 8 + od) * 4096 + oh * 64 + 8 * g;
    float4 lo, hi;
    lo.x = fmaxf(acc[co][0], 0.0f); lo.y = fmaxf(acc[co][1], 0.0f);
    lo.z = fmaxf(acc[co][2], 0.0f); lo.w = fmaxf(acc[co][3], 0.0f);
    hi.x = fmaxf(acc[co][4], 0.0f); hi.y = fmaxf(acc[co][5], 0.0f);
    hi.z = fmaxf(acc[co][6], 0.0f); hi.w = fmaxf(acc[co][7], 0.0f);
    st4(op, lo); st4(op + 4, hi);
  }
}

// ============ deconv3 v3 (strip — measured improvement, kept) ============
// d1 (16,8,8,64,64) -> d2 (16,4,16,128,128), k4 s2 p1 + relu.
// Grid: ph(2) x blh(4) x od(16) x n(16) = 2048 blocks; block = g(16) x bl(16).
__global__ __launch_bounds__(256) void deconv3_k(
    const float* __restrict__ d1, const float* __restrict__ w,
    const float* __restrict__ bias, float* __restrict__ d2) {
  int bid = blockIdx.x;
  int ph  = bid & 1;
  int blh = (bid >> 1) & 3;
  int od  = (bid >> 3) & 15;
  int n   = bid >> 7;
  int tid = threadIdx.x;
  int g   = tid & 15;       // ow strip 8g..8g+7; input cols 4g-1..4g+4
  int bl  = tid >> 4;       // 0..15
  int BL  = blh * 16 + bl;  // oh = 2*BL + ph
  bool glf = (g > 0), grf = (g < 15);

  int kd0 = (od + 1) & 1;
  int idtop = (od + 1 - kd0) >> 1;  // id = idtop - jd, kd = kd0 + 2*jd
  int kh0 = (ph + 1) & 1;
  int ihtop = BL + ph;              // ih = ihtop - jh, kh = kh0 + 2*jh

  float acc[4][8];
  #pragma unroll
  for (int co = 0; co < 4; co++) {
    float bv = bias[co];
    #pragma unroll
    for (int m = 0; m < 8; m++) acc[co][m] = bv;
  }

  #pragma unroll 1
  for (int ci = 0; ci < 8; ci++) {
    const float* ip = d1 + ((n * 8 + ci) * 8) * 4096;
    #pragma unroll
    for (int jd = 0; jd < 2; jd++) {
      int id = idtop - jd;
      bool vd = (unsigned)id < 8u;
      int idc = vd ? id : 0;
      const float* plane = ip + idc * 4096;
      #pragma unroll
      for (int jh = 0; jh < 2; jh++) {
        int ih = ihtop - jh;
        bool v = vd && ((unsigned)ih < 64u);
        int ihc = (unsigned)ih < 64u ? ih : 0;
        const float* rp = plane + ihc * 64 + 4 * g;
        float r[6];
        float4 A = ld4(rp);
        float rl = rp[-1 * (int)glf];
        float rr = rp[grf ? 4 : 0];
        r[0] = (v && glf) ? rl : 0.0f;
        r[1] = v ? A.x : 0.0f; r[2] = v ? A.y : 0.0f;
        r[3] = v ? A.z : 0.0f; r[4] = v ? A.w : 0.0f;
        r[5] = (v && grf) ? rr : 0.0f;
        int kd = kd0 + 2 * jd;
        int kh = kh0 + 2 * jh;
        #pragma unroll
        for (int co = 0; co < 4; co++) {
          const float* wb = w + ((ci * 4 + co) * 4 + kd) * 16 + kh * 4;
          #pragma unroll
          for (int jw = 0; jw < 2; jw++) {
            float w_ev = wb[1 + 2 * jw];  // kw for even ow (pw=0)
            float w_od = wb[2 * jw];      // kw for odd  ow (pw=1)
            #pragma unroll
            for (int ii = 0; ii < 4; ii++) {
              acc[co][2 * ii]     += r[ii + 1 - jw] * w_ev;
              acc[co][2 * ii + 1] += r[ii + 2 - jw] * w_od;
            }
          }
        }
      }
    }
  }
  int oh = 2 * BL + ph;
  #pragma unroll
  for (int co = 0; co < 4; co++) {
    float* op = d2 + ((n * 4 + co) * 16 + od) * 16384 + oh * 128 + 8 * g;
    float4 lo, hi;
    lo.x = fmaxf(acc[co][0], 0.0f); lo.y = fmaxf(acc[co][1], 0.0f);
    lo.z = fmaxf(acc[co][2], 0.0f); lo.w = fmaxf(acc[co][3], 0.0f);
    hi.x = fmaxf(acc[co][4], 0.0f); hi.y = fmaxf(acc[co][5], 0.0f);
    hi.z = fmaxf(acc[co][6], 0.0f); hi.w = fmaxf(acc[co][7], 0.0f);
    st4(op, lo); st4(op + 4, hi);
  }
}

// ============ deconv4 (R2 register-cube — verified 78.6µs) ============
// Strip (112.9µs) and LDS-staged (125.8µs, 16M bank conflicts + 2.4x FETCH)
// both regressed: the cube's constant-offset load clusters have the best
// MLP + cache interleaving. thread = 2x2x2 pos x 3 co. 2048 blocks.
__global__ __launch_bounds__(256) void deconv4_k(
    const float* __restrict__ d2, const float* __restrict__ w,
    const float* __restrict__ bias, float* __restrict__ out) {
  int idx = blockIdx.x * 256 + threadIdx.x;
  int c = idx & 63;
  int b = (idx >> 6) & 63;
  int a = (idx >> 12) & 7;
  int n = idx >> 15;
  float acc[2][2][2][3];
  #pragma unroll
  for (int pd = 0; pd < 2; pd++)
    #pragma unroll
    for (int ph = 0; ph < 2; ph++)
      #pragma unroll
      for (int pw = 0; pw < 2; pw++)
        #pragma unroll
        for (int co = 0; co < 3; co++) acc[pd][ph][pw][co] = bias[co];
  int ih0 = 2 * b - 1, iw0 = 2 * c - 1;
  bool vh[4], vw[4];
  #pragma unroll
  for (int l = 0; l < 4; l++) {
    vh[l] = (unsigned)(ih0 + l) < 128u;
    vw[l] = (unsigned)(iw0 + l) < 128u;
  }
  #pragma unroll 1
  for (int ci = 0; ci < 4; ci++) {
    const float* ip = d2 + ((n * 4 + ci) * 16) * 16384;
    #pragma unroll
    for (int ld = 0; ld < 4; ld++) {
      int id = 2 * a - 1 + ld;
      bool vdl = (unsigned)id < 16u;
      const float* pp = ip + id * 16384;
      float p[4][4];
      #pragma unroll
      for (int lh = 0; lh < 4; lh++)
        #pragma unroll
        for (int lw = 0; lw < 4; lw++)
          p[lh][lw] = (vdl && vh[lh] && vw[lw]) ? pp[(ih0 + lh) * 128 + (iw0 + lw)] : 0.0f;
      #pragma unroll
      for (int pd = 0; pd < 2; pd++) {
        int kd = pd + 2 - ld;
        if (kd < 0 || kd > 2) continue;
        #pragma unroll
        for (int kh = 0; kh < 3; kh++)
          #pragma unroll
          for (int kw = 0; kw < 3; kw++)
            #pragma unroll
            for (int co = 0; co < 3; co++) {
              float wv = w[(ci * 3 + co) * 27 + kd * 9 + kh * 3 + kw];
              #pragma unroll
              for (int ph = 0; ph < 2; ph++)
                #pragma unroll
                for (int pw = 0; pw < 2; pw++)
                  acc[pd][ph][pw][co] += p[ph + 2 - kh][pw + 2 - kw] * wv;
            }
      }
    }
  }
  #pragma unroll
  for (int co = 0; co < 3; co++)
    #pragma unroll
    for (int pd = 0; pd < 2; pd++)
      #pragma unroll
      for (int ph = 0; ph < 2; ph++)
        #pragma unroll
        for (int pw = 0; pw < 2; pw++)
          out[((n * 3 + co) * 16 + 2 * a + pd) * 16384 +
              (2 * b + ph) * 128 + (2 * c + pw)] = acc[pd][ph][pw][co];
}

extern "C" void kernel_launch(void* const* d_in, const int* in_sizes, int n_in,
                              void* d_out, int out_size, void* d_ws, size_t ws_size,
                              hipStream_t stream) {
  const float* x      = (const float*)d_in[0];
  const float* enc_w1 = (const float*)d_in[2];
  const float* enc_b1 = (const float*)d_in[3];
  const float* enc_w2 = (const float*)d_in[4];
  const float* enc_b2 = (const float*)d_in[5];
  const float* enc_w4 = (const float*)d_in[6];
  const float* enc_b4 = (const float*)d_in[7];
  const float* dec_w1 = (const float*)d_in[8];
  const float* dec_b1 = (const float*)d_in[9];
  const float* dec_w3 = (const float*)d_in[10];
  const float* dec_b3 = (const float*)d_in[11];
  const float* dec_w4 = (const float*)d_in[12];
  const float* dec_b4 = (const float*)d_in[13];
  const float* emb    = (const float*)d_in[14];
  const float* csize  = (const float*)d_in[15];

  float* ws = (float*)d_ws;
  float* stats = ws;                      // 64
  float* quant = ws + 64;                 // 1,048,576
  // (z slot retained in layout but unused — conv4+VQ fused in-register)
  float* y2    = ws + 64 + 2 * 1048576;   // 524,288
  float* y1    = y2 + 524288;             // 2,097,152 (dead after conv2)
  float* d1    = ws + 64 + 1048576;       // 4,194,304 (reuses z/y2/y1 region)
  float* d2    = ws + 64 + 1048576 + 4194304;  // 16,777,216

  float* out   = (float*)d_out;                        // 12,582,912
  float* out_loss  = out + 12582912;
  float* out_codes = out_loss + 1;                     // 65,536
  float* out_perp  = out_codes + 65536;
  float* out_used  = out_perp + 1;

  init_stats_k<<<1, 64, 0, stream>>>(stats);

  conv1_k<<<512, 256, 0, stream>>>(x, enc_w1, enc_b1, y1);
  conv2_k<<<512, 256, 0, stream>>>(y1, enc_w2, enc_b2, y2);

  conv4vq_k<<<256, 256, 0, stream>>>(y2, enc_w4, enc_b4, emb, quant, out_codes, stats);
  fin_k<<<1, 64, 0, stream>>>(stats, csize, out_loss, out_perp, out_used);

  deconv1_k<<<512, 256, 0, stream>>>(quant, dec_w1, dec_b1, d1);
  deconv3_k<<<2048, 256, 0, stream>>>(d1, dec_w3, dec_b3, d2);
  deconv4_k<<<2048, 256, 0, stream>>>(d2, dec_w4, dec_b4, out);
}

// Round 6
// 378.995 us; speedup vs baseline: 1.1115x; 1.0625x over previous
//
#include <hip/hip_runtime.h>
#include <math.h>

#define NB 16

// ---------------- shapes ----------------
// x:      (16, 3,16,128,128)
// y1:     (16, 4, 8, 64, 64)   conv1 k4 s2 p1 + relu
// y2:     (16, 8, 4, 32, 32)   conv2 k4 s2 p1 + relu
// z:      (in-register/LDS)    conv4 k3 s1 p1 + clip(0,6), fused with VQ
// quant:  (16,16, 4, 32, 32)   VQ
// d1:     (16, 8, 8, 64, 64)   deconv1 k4 s2 p1 + relu
// d2:     (16, 4,16,128,128)   deconv3 k4 s2 p1 + relu
// out:    (16, 3,16,128,128)   deconv4 k3 s1 p1

__device__ __forceinline__ float4 ld4(const float* p) {
  return *reinterpret_cast<const float4*>(p);
}
__device__ __forceinline__ void st4(float* p, float4 v) {
  *reinterpret_cast<float4*>(p) = v;
}

// conv1 (R4 strip, measured fast): thread = 4 co x (1 od, 1 oh, 4 ow). 512 blocks.
__global__ __launch_bounds__(256) void conv1_k(
    const float* __restrict__ x, const float* __restrict__ w,
    const float* __restrict__ bias, float* __restrict__ y) {
  int idx = blockIdx.x * 256 + threadIdx.x;
  int g  = idx & 15;
  int oh = (idx >> 4) & 63;
  int od = (idx >> 10) & 7;
  int n  = idx >> 13;
  bool gl = (g > 0), gr = (g < 15);
  float acc[4][4];
  #pragma unroll
  for (int co = 0; co < 4; co++) {
    float bv = bias[co];
    #pragma unroll
    for (int m = 0; m < 4; m++) acc[co][m] = bv;
  }
  int ih0 = 2 * oh - 1;
  #pragma unroll 1
  for (int ci = 0; ci < 3; ci++) {
    #pragma unroll 1
    for (int kd = 0; kd < 4; kd++) {
      int id = 2 * od - 1 + kd;
      bool vd = (unsigned)id < 16u;
      int idc = vd ? id : 0;
      const float* plane = x + (((n * 3 + ci) * 16 + idc) * 16384);
      #pragma unroll
      for (int kh = 0; kh < 4; kh++) {
        int ih = ih0 + kh;
        bool v = vd && ((unsigned)ih < 128u);
        int ihc = (unsigned)ih < 128u ? ih : 0;
        const float* rp = plane + ihc * 128 + 8 * g;
        float r[10];
        float4 A = ld4(rp);
        float4 B = ld4(rp + 4);
        float rl = rp[-1 * (int)gl];
        float rr = rp[gr ? 8 : 0];
        r[0] = (v && gl) ? rl : 0.0f;
        r[1] = v ? A.x : 0.0f; r[2] = v ? A.y : 0.0f;
        r[3] = v ? A.z : 0.0f; r[4] = v ? A.w : 0.0f;
        r[5] = v ? B.x : 0.0f; r[6] = v ? B.y : 0.0f;
        r[7] = v ? B.z : 0.0f; r[8] = v ? B.w : 0.0f;
        r[9] = (v && gr) ? rr : 0.0f;
        #pragma unroll
        for (int co = 0; co < 4; co++) {
          const float* wb = w + ((co * 3 + ci) * 4 + kd) * 16 + kh * 4;
          #pragma unroll
          for (int kw = 0; kw < 4; kw++) {
            float wv = wb[kw];
            #pragma unroll
            for (int m = 0; m < 4; m++)
              acc[co][m] += r[2 * m + kw] * wv;
          }
        }
      }
    }
  }
  #pragma unroll
  for (int co = 0; co < 4; co++) {
    float4 o;
    o.x = fmaxf(acc[co][0], 0.0f); o.y = fmaxf(acc[co][1], 0.0f);
    o.z = fmaxf(acc[co][2], 0.0f); o.w = fmaxf(acc[co][3], 0.0f);
    st4(y + ((n * 4 + co) * 8 + od) * 4096 + oh * 64 + 4 * g, o);
  }
}

// conv2: thread = 1 pos x 4 co. 512 blocks.
__global__ __launch_bounds__(256) void conv2_k(
    const float* __restrict__ y1, const float* __restrict__ w,
    const float* __restrict__ bias, float* __restrict__ y) {
  int idx = blockIdx.x * 256 + threadIdx.x;
  int ow = idx & 31;
  int oh = (idx >> 5) & 31;
  int od = (idx >> 10) & 3;
  int n = (idx >> 12) & 15;
  int cog = idx >> 16;
  float acc[4];
  #pragma unroll
  for (int co = 0; co < 4; co++) acc[co] = bias[cog * 4 + co];
  int id0 = 2 * od - 1, ih0 = 2 * oh - 1, iw0 = 2 * ow - 1;
  bool vh[4], vw[4];
  #pragma unroll
  for (int l = 0; l < 4; l++) {
    vh[l] = (unsigned)(ih0 + l) < 64u;
    vw[l] = (unsigned)(iw0 + l) < 64u;
  }
  #pragma unroll 1
  for (int ci = 0; ci < 4; ci++) {
    const float* ip = y1 + ((n * 4 + ci) * 8) * 4096;
    #pragma unroll
    for (int kd = 0; kd < 4; kd++) {
      int id = id0 + kd;
      bool vd = (unsigned)id < 8u;
      const float* pp = ip + id * 4096;
      float p[4][4];
      #pragma unroll
      for (int kh = 0; kh < 4; kh++)
        #pragma unroll
        for (int kw = 0; kw < 4; kw++)
          p[kh][kw] = (vd && vh[kh] && vw[kw]) ? pp[(ih0 + kh) * 64 + (iw0 + kw)] : 0.0f;
      #pragma unroll
      for (int co = 0; co < 4; co++) {
        const float* wp = w + (((cog * 4 + co) * 4 + ci) * 4 + kd) * 16;
        #pragma unroll
        for (int kh = 0; kh < 4; kh++)
          #pragma unroll
          for (int kw = 0; kw < 4; kw++)
            acc[co] += p[kh][kw] * wp[kh * 4 + kw];
      }
    }
  }
  #pragma unroll
  for (int co = 0; co < 4; co++)
    y[((n * 8 + cog * 4 + co) * 4 + od) * 1024 + oh * 32 + ow] = fmaxf(acc[co], 0.0f);
}

// ============ conv4 + VQ fused v2 (restored parallelism) ============
// Grid: ohg(16) x od(4) x n(16) = 1024 blocks; block = pos(64) x cog(4).
// Phase 1: verified conv4_k body (4 co/thread, 16 waves/CU) -> z in LDS.
// Phase 2: wave 0 (64 threads) runs verified vq_k body per position from LDS.
__global__ __launch_bounds__(256) void conv4vq_k(
    const float* __restrict__ y2, const float* __restrict__ w,
    const float* __restrict__ bias, const float* __restrict__ emb,
    float* __restrict__ quant, float* __restrict__ codes_out,
    float* __restrict__ stats) {
  __shared__ float se[32 * 16];
  __shared__ float se2[32];
  __shared__ float shist[32];
  __shared__ float zsh[64][17];   // stride 17: conflict-free write/read
  int tid = threadIdx.x;
  for (int i = tid; i < 512; i += 256) {
    int r = i >> 4;
    float v = emb[i];
    if (r == 0) v = 0.0f;
    else if (r == 1) v = 6.0f;
    se[i] = v;
  }
  if (tid < 32) shist[tid] = 0.0f;
  __syncthreads();
  if (tid < 32) {
    float s = 0.0f;
    #pragma unroll
    for (int d = 0; d < 16; d++) { float v = se[tid * 16 + d]; s += v * v; }
    se2[tid] = s;
  }

  int bid = blockIdx.x;
  int ohg = bid & 15;
  int od  = (bid >> 4) & 3;
  int n   = bid >> 6;
  int pos = tid & 63;
  int cog = tid >> 6;
  int ow  = pos & 31;
  int oh  = ohg * 2 + (pos >> 5);

  // ---- conv4 (verbatim verified body; 4 co per thread) ----
  float acc[4];
  #pragma unroll
  for (int co = 0; co < 4; co++) acc[co] = bias[cog * 4 + co];
  bool vh[3], vw[3];
  #pragma unroll
  for (int l = 0; l < 3; l++) {
    vh[l] = (unsigned)(oh - 1 + l) < 32u;
    vw[l] = (unsigned)(ow - 1 + l) < 32u;
  }
  #pragma unroll 1
  for (int ci = 0; ci < 8; ci++) {
    const float* ip = y2 + ((n * 8 + ci) * 4) * 1024;
    #pragma unroll
    for (int kd = 0; kd < 3; kd++) {
      int id = od - 1 + kd;
      bool vd = (unsigned)id < 4u;
      const float* pp = ip + id * 1024;
      float p[3][3];
      #pragma unroll
      for (int kh = 0; kh < 3; kh++)
        #pragma unroll
        for (int kw = 0; kw < 3; kw++)
          p[kh][kw] = (vd && vh[kh] && vw[kw]) ? pp[(oh - 1 + kh) * 32 + (ow - 1 + kw)] : 0.0f;
      #pragma unroll
      for (int co = 0; co < 4; co++) {
        const float* wp = w + (((cog * 4 + co) * 8 + ci) * 3 + kd) * 9;
        #pragma unroll
        for (int kh = 0; kh < 3; kh++)
          #pragma unroll
          for (int kw = 0; kw < 3; kw++)
            acc[co] += p[kh][kw] * wp[kh * 3 + kw];
      }
    }
  }
  #pragma unroll
  for (int co = 0; co < 4; co++)
    zsh[pos][cog * 4 + co] = fminf(fmaxf(acc[co], 0.0f), 6.0f);
  __syncthreads();

  // ---- VQ (verbatim verified vq_k body; wave 0, one position/lane) ----
  if (tid < 64) {
    float f[16];
    float f2 = 0.0f;
    #pragma unroll
    for (int c = 0; c < 16; c++) { float v = zsh[tid][c]; f[c] = v; f2 += v * v; }
    float best = 1e30f; int bi = 0;
    for (int e = 0; e < 32; e++) {
      float dot = 0.0f;
      #pragma unroll
      for (int c = 0; c < 16; c++) dot += f[c] * se[e * 16 + c];
      float d2 = f2 - 2.0f * dot + se2[e];
      if (d2 < best) { best = d2; bi = e; }
    }
    int poh = ohg * 2 + (tid >> 5);
    int pow_ = tid & 31;
    float* qp = quant + n * 65536 + od * 1024 + poh * 32 + pow_;
    float lsum = 0.0f;
    #pragma unroll
    for (int c = 0; c < 16; c++) {
      float q = se[bi * 16 + c];
      qp[c * 4096] = q;
      float df = q - f[c];
      lsum += df * df;
    }
    codes_out[n * 4096 + od * 1024 + poh * 32 + pow_] = (float)bi;
    atomicAdd(&shist[bi], 1.0f);
    for (int o = 32; o; o >>= 1) lsum += __shfl_down(lsum, o);
    if (tid == 0) atomicAdd(&stats[0], lsum);
  }
  __syncthreads();
  if (tid < 32) {
    float h = shist[tid];
    if (h != 0.0f) atomicAdd(&stats[1 + tid], h);
  }
}

__global__ void init_stats_k(float* __restrict__ stats) {
  int tid = threadIdx.x;
  if (tid < 33) stats[tid] = 0.0f;
}

__global__ void fin_k(const float* __restrict__ stats,
                      const float* __restrict__ cluster_size,
                      float* __restrict__ out_loss, float* __restrict__ out_perp,
                      float* __restrict__ out_used) {
  int tid = threadIdx.x;
  float v = 0.0f;
  float used = 0.0f;
  if (tid < 32) {
    float p = stats[1 + tid] * (1.0f / 65536.0f);
    v = p * logf(p + 1e-10f);
    used = (cluster_size[tid] > 1e-5f) ? 1.0f : 0.0f;
  }
  for (int o = 16; o; o >>= 1) { v += __shfl_down(v, o); used += __shfl_down(used, o); }
  if (tid == 0) {
    *out_perp = expf(-v);
    *out_used = used * (1.0f / 32.0f);
    *out_loss = 0.25f * stats[0] * (1.0f / 1048576.0f);
  }
}

// ============ deconv1 v3 (strip, unchanged) ============
// quant (16,16,4,32,32) -> d1 (16,8,8,64,64), k4 s2 p1.
// Grid: cog(2) x ph(2) x od(8) x n(16) = 512 blocks; block = g(8) x bl(32).
__global__ __launch_bounds__(256) void deconv1_k(
    const float* __restrict__ q, const float* __restrict__ w,
    const float* __restrict__ bias, float* __restrict__ d1) {
  int bid = blockIdx.x;
  int cog = bid & 1;
  int ph  = (bid >> 1) & 1;
  int od  = (bid >> 2) & 7;
  int n   = bid >> 5;
  int tid = threadIdx.x;
  int g   = tid & 7;     // ow strip 8g..8g+7; input cols 4g-1..4g+4
  int bl  = tid >> 3;    // 0..31; oh = 2*bl + ph
  bool glf = (g > 0), grf = (g < 7);

  int kd0 = (od + 1) & 1;
  int idtop = (od + 1 - kd0) >> 1;  // id = idtop - jd, kd = kd0 + 2*jd
  int kh0 = (ph + 1) & 1;
  int ihtop = bl + ph;              // ih = ihtop - jh, kh = kh0 + 2*jh

  float acc[4][8];
  #pragma unroll
  for (int co = 0; co < 4; co++) {
    float bv = bias[cog * 4 + co];
    #pragma unroll
    for (int m = 0; m < 8; m++) acc[co][m] = bv;
  }

  #pragma unroll 1
  for (int ci = 0; ci < 16; ci++) {
    const float* ip = q + ((n * 16 + ci) * 4) * 1024;
    #pragma unroll
    for (int jd = 0; jd < 2; jd++) {
      int id = idtop - jd;
      bool vd = (unsigned)id < 4u;
      int idc = vd ? id : 0;
      const float* plane = ip + idc * 1024;
      #pragma unroll
      for (int jh = 0; jh < 2; jh++) {
        int ih = ihtop - jh;
        bool v = vd && ((unsigned)ih < 32u);
        int ihc = (unsigned)ih < 32u ? ih : 0;
        const float* rp = plane + ihc * 32 + 4 * g;
        float r[6];
        float4 A = ld4(rp);
        float rl = rp[-1 * (int)glf];
        float rr = rp[grf ? 4 : 0];
        r[0] = (v && glf) ? rl : 0.0f;
        r[1] = v ? A.x : 0.0f; r[2] = v ? A.y : 0.0f;
        r[3] = v ? A.z : 0.0f; r[4] = v ? A.w : 0.0f;
        r[5] = (v && grf) ? rr : 0.0f;
        int kd = kd0 + 2 * jd;
        int kh = kh0 + 2 * jh;
        #pragma unroll
        for (int co = 0; co < 4; co++) {
          const float* wb = w + ((ci * 8 + cog * 4 + co) * 4 + kd) * 16 + kh * 4;
          #pragma unroll
          for (int jw = 0; jw < 2; jw++) {
            float w_ev = wb[1 + 2 * jw];  // kw for even ow (pw=0)
            float w_od = wb[2 * jw];      // kw for odd  ow (pw=1)
            #pragma unroll
            for (int ii = 0; ii < 4; ii++) {
              acc[co][2 * ii]     += r[ii + 1 - jw] * w_ev;
              acc[co][2 * ii + 1] += r[ii + 2 - jw] * w_od;
            }
          }
        }
      }
    }
  }
  int oh = 2 * bl + ph;
  #pragma unroll
  for (int co = 0; co < 4; co++) {
    float* op = d1 + ((n * 8 + cog * 4 + co) * 8 + od) * 4096 + oh * 64 + 8 * g;
    float4 lo, hi;
    lo.x = fmaxf(acc[co][0], 0.0f); lo.y = fmaxf(acc[co][1], 0.0f);
    lo.z = fmaxf(acc[co][2], 0.0f); lo.w = fmaxf(acc[co][3], 0.0f);
    hi.x = fmaxf(acc[co][4], 0.0f); hi.y = fmaxf(acc[co][5], 0.0f);
    hi.z = fmaxf(acc[co][6], 0.0f); hi.w = fmaxf(acc[co][7], 0.0f);
    st4(op, lo); st4(op + 4, hi);
  }
}

// ============ deconv3 v3 (strip — measured improvement, kept) ============
// d1 (16,8,8,64,64) -> d2 (16,4,16,128,128), k4 s2 p1 + relu.
// Grid: ph(2) x blh(4) x od(16) x n(16) = 2048 blocks; block = g(16) x bl(16).
__global__ __launch_bounds__(256) void deconv3_k(
    const float* __restrict__ d1, const float* __restrict__ w,
    const float* __restrict__ bias, float* __restrict__ d2) {
  int bid = blockIdx.x;
  int ph  = bid & 1;
  int blh = (bid >> 1) & 3;
  int od  = (bid >> 3) & 15;
  int n   = bid >> 7;
  int tid = threadIdx.x;
  int g   = tid & 15;       // ow strip 8g..8g+7; input cols 4g-1..4g+4
  int bl  = tid >> 4;       // 0..15
  int BL  = blh * 16 + bl;  // oh = 2*BL + ph
  bool glf = (g > 0), grf = (g < 15);

  int kd0 = (od + 1) & 1;
  int idtop = (od + 1 - kd0) >> 1;  // id = idtop - jd, kd = kd0 + 2*jd
  int kh0 = (ph + 1) & 1;
  int ihtop = BL + ph;              // ih = ihtop - jh, kh = kh0 + 2*jh

  float acc[4][8];
  #pragma unroll
  for (int co = 0; co < 4; co++) {
    float bv = bias[co];
    #pragma unroll
    for (int m = 0; m < 8; m++) acc[co][m] = bv;
  }

  #pragma unroll 1
  for (int ci = 0; ci < 8; ci++) {
    const float* ip = d1 + ((n * 8 + ci) * 8) * 4096;
    #pragma unroll
    for (int jd = 0; jd < 2; jd++) {
      int id = idtop - jd;
      bool vd = (unsigned)id < 8u;
      int idc = vd ? id : 0;
      const float* plane = ip + idc * 4096;
      #pragma unroll
      for (int jh = 0; jh < 2; jh++) {
        int ih = ihtop - jh;
        bool v = vd && ((unsigned)ih < 64u);
        int ihc = (unsigned)ih < 64u ? ih : 0;
        const float* rp = plane + ihc * 64 + 4 * g;
        float r[6];
        float4 A = ld4(rp);
        float rl = rp[-1 * (int)glf];
        float rr = rp[grf ? 4 : 0];
        r[0] = (v && glf) ? rl : 0.0f;
        r[1] = v ? A.x : 0.0f; r[2] = v ? A.y : 0.0f;
        r[3] = v ? A.z : 0.0f; r[4] = v ? A.w : 0.0f;
        r[5] = (v && grf) ? rr : 0.0f;
        int kd = kd0 + 2 * jd;
        int kh = kh0 + 2 * jh;
        #pragma unroll
        for (int co = 0; co < 4; co++) {
          const float* wb = w + ((ci * 4 + co) * 4 + kd) * 16 + kh * 4;
          #pragma unroll
          for (int jw = 0; jw < 2; jw++) {
            float w_ev = wb[1 + 2 * jw];  // kw for even ow (pw=0)
            float w_od = wb[2 * jw];      // kw for odd  ow (pw=1)
            #pragma unroll
            for (int ii = 0; ii < 4; ii++) {
              acc[co][2 * ii]     += r[ii + 1 - jw] * w_ev;
              acc[co][2 * ii + 1] += r[ii + 2 - jw] * w_od;
            }
          }
        }
      }
    }
  }
  int oh = 2 * BL + ph;
  #pragma unroll
  for (int co = 0; co < 4; co++) {
    float* op = d2 + ((n * 4 + co) * 16 + od) * 16384 + oh * 128 + 8 * g;
    float4 lo, hi;
    lo.x = fmaxf(acc[co][0], 0.0f); lo.y = fmaxf(acc[co][1], 0.0f);
    lo.z = fmaxf(acc[co][2], 0.0f); lo.w = fmaxf(acc[co][3], 0.0f);
    hi.x = fmaxf(acc[co][4], 0.0f); hi.y = fmaxf(acc[co][5], 0.0f);
    hi.z = fmaxf(acc[co][6], 0.0f); hi.w = fmaxf(acc[co][7], 0.0f);
    st4(op, lo); st4(op + 4, hi);
  }
}

// ============ deconv4 (R2 register-cube — verified 78.6µs) ============
// Strip (112.9µs) and LDS-staged (125.8µs) both regressed; cube's
// constant-offset load clusters have the best MLP + cache interleaving.
__global__ __launch_bounds__(256) void deconv4_k(
    const float* __restrict__ d2, const float* __restrict__ w,
    const float* __restrict__ bias, float* __restrict__ out) {
  int idx = blockIdx.x * 256 + threadIdx.x;
  int c = idx & 63;
  int b = (idx >> 6) & 63;
  int a = (idx >> 12) & 7;
  int n = idx >> 15;
  float acc[2][2][2][3];
  #pragma unroll
  for (int pd = 0; pd < 2; pd++)
    #pragma unroll
    for (int ph = 0; ph < 2; ph++)
      #pragma unroll
      for (int pw = 0; pw < 2; pw++)
        #pragma unroll
        for (int co = 0; co < 3; co++) acc[pd][ph][pw][co] = bias[co];
  int ih0 = 2 * b - 1, iw0 = 2 * c - 1;
  bool vh[4], vw[4];
  #pragma unroll
  for (int l = 0; l < 4; l++) {
    vh[l] = (unsigned)(ih0 + l) < 128u;
    vw[l] = (unsigned)(iw0 + l) < 128u;
  }
  #pragma unroll 1
  for (int ci = 0; ci < 4; ci++) {
    const float* ip = d2 + ((n * 4 + ci) * 16) * 16384;
    #pragma unroll
    for (int ld = 0; ld < 4; ld++) {
      int id = 2 * a - 1 + ld;
      bool vdl = (unsigned)id < 16u;
      const float* pp = ip + id * 16384;
      float p[4][4];
      #pragma unroll
      for (int lh = 0; lh < 4; lh++)
        #pragma unroll
        for (int lw = 0; lw < 4; lw++)
          p[lh][lw] = (vdl && vh[lh] && vw[lw]) ? pp[(ih0 + lh) * 128 + (iw0 + lw)] : 0.0f;
      #pragma unroll
      for (int pd = 0; pd < 2; pd++) {
        int kd = pd + 2 - ld;
        if (kd < 0 || kd > 2) continue;
        #pragma unroll
        for (int kh = 0; kh < 3; kh++)
          #pragma unroll
          for (int kw = 0; kw < 3; kw++)
            #pragma unroll
            for (int co = 0; co < 3; co++) {
              float wv = w[(ci * 3 + co) * 27 + kd * 9 + kh * 3 + kw];
              #pragma unroll
              for (int ph = 0; ph < 2; ph++)
                #pragma unroll
                for (int pw = 0; pw < 2; pw++)
                  acc[pd][ph][pw][co] += p[ph + 2 - kh][pw + 2 - kw] * wv;
            }
      }
    }
  }
  #pragma unroll
  for (int co = 0; co < 3; co++)
    #pragma unroll
    for (int pd = 0; pd < 2; pd++)
      #pragma unroll
      for (int ph = 0; ph < 2; ph++)
        #pragma unroll
        for (int pw = 0; pw < 2; pw++)
          out[((n * 3 + co) * 16 + 2 * a + pd) * 16384 +
              (2 * b + ph) * 128 + (2 * c + pw)] = acc[pd][ph][pw][co];
}

extern "C" void kernel_launch(void* const* d_in, const int* in_sizes, int n_in,
                              void* d_out, int out_size, void* d_ws, size_t ws_size,
                              hipStream_t stream) {
  const float* x      = (const float*)d_in[0];
  const float* enc_w1 = (const float*)d_in[2];
  const float* enc_b1 = (const float*)d_in[3];
  const float* enc_w2 = (const float*)d_in[4];
  const float* enc_b2 = (const float*)d_in[5];
  const float* enc_w4 = (const float*)d_in[6];
  const float* enc_b4 = (const float*)d_in[7];
  const float* dec_w1 = (const float*)d_in[8];
  const float* dec_b1 = (const float*)d_in[9];
  const float* dec_w3 = (const float*)d_in[10];
  const float* dec_b3 = (const float*)d_in[11];
  const float* dec_w4 = (const float*)d_in[12];
  const float* dec_b4 = (const float*)d_in[13];
  const float* emb    = (const float*)d_in[14];
  const float* csize  = (const float*)d_in[15];

  float* ws = (float*)d_ws;
  float* stats = ws;                      // 64
  float* quant = ws + 64;                 // 1,048,576
  // (z slot retained in layout but unused — conv4+VQ fused)
  float* y2    = ws + 64 + 2 * 1048576;   // 524,288
  float* y1    = y2 + 524288;             // 2,097,152 (dead after conv2)
  float* d1    = ws + 64 + 1048576;       // 4,194,304 (reuses z/y2/y1 region)
  float* d2    = ws + 64 + 1048576 + 4194304;  // 16,777,216

  float* out   = (float*)d_out;                        // 12,582,912
  float* out_loss  = out + 12582912;
  float* out_codes = out_loss + 1;                     // 65,536
  float* out_perp  = out_codes + 65536;
  float* out_used  = out_perp + 1;

  init_stats_k<<<1, 64, 0, stream>>>(stats);

  conv1_k<<<512, 256, 0, stream>>>(x, enc_w1, enc_b1, y1);
  conv2_k<<<512, 256, 0, stream>>>(y1, enc_w2, enc_b2, y2);

  conv4vq_k<<<1024, 256, 0, stream>>>(y2, enc_w4, enc_b4, emb, quant, out_codes, stats);
  fin_k<<<1, 64, 0, stream>>>(stats, csize, out_loss, out_perp, out_used);

  deconv1_k<<<512, 256, 0, stream>>>(quant, dec_w1, dec_b1, d1);
  deconv3_k<<<2048, 256, 0, stream>>>(d1, dec_w3, dec_b3, d2);
  deconv4_k<<<2048, 256, 0, stream>>>(d2, dec_w4, dec_b4, out);
}

// Round 7
// 359.754 us; speedup vs baseline: 1.1710x; 1.0535x over previous
//
#include <hip/hip_runtime.h>
#include <math.h>

#define NB 16

// ---------------- shapes ----------------
// x:      (16, 3,16,128,128)
// y1:     (16, 4, 8, 64, 64)   conv1 k4 s2 p1 + relu
// y2:     (16, 8, 4, 32, 32)   conv2 k4 s2 p1 + relu
// z:      (16,16, 4, 32, 32)   conv4 k3 s1 p1 + clip(0,6)
// quant:  (16,16, 4, 32, 32)   VQ
// d1:     (16, 8, 8, 64, 64)   deconv1 k4 s2 p1 + relu
// d2:     (16, 4,16,128,128)   deconv3 k4 s2 p1 + relu   (padded variant: [18][130][136])
// out:    (16, 3,16,128,128)   deconv4 k3 s1 p1

// padded d2 geometry
#define P_STRIDE 136              // col = iw + 4 (iw in -1..128 -> 3..132); st4 stays 16B-aligned
#define P_PLANE  (130 * P_STRIDE) // 17680 ; row = ih + 1 (ih in -1..128 -> 0..129)
#define P_VOL    (18 * P_PLANE)   // 318240; plane = id + 1 (id in -1..16 -> 0..17)

__device__ __forceinline__ float4 ld4(const float* p) {
  return *reinterpret_cast<const float4*>(p);
}
__device__ __forceinline__ void st4(float* p, float4 v) {
  *reinterpret_cast<float4*>(p) = v;
}

// conv1 (R4 strip, measured fast): thread = 4 co x (1 od, 1 oh, 4 ow). 512 blocks.
__global__ __launch_bounds__(256) void conv1_k(
    const float* __restrict__ x, const float* __restrict__ w,
    const float* __restrict__ bias, float* __restrict__ y) {
  int idx = blockIdx.x * 256 + threadIdx.x;
  int g  = idx & 15;
  int oh = (idx >> 4) & 63;
  int od = (idx >> 10) & 7;
  int n  = idx >> 13;
  bool gl = (g > 0), gr = (g < 15);
  float acc[4][4];
  #pragma unroll
  for (int co = 0; co < 4; co++) {
    float bv = bias[co];
    #pragma unroll
    for (int m = 0; m < 4; m++) acc[co][m] = bv;
  }
  int ih0 = 2 * oh - 1;
  #pragma unroll 1
  for (int ci = 0; ci < 3; ci++) {
    #pragma unroll 1
    for (int kd = 0; kd < 4; kd++) {
      int id = 2 * od - 1 + kd;
      bool vd = (unsigned)id < 16u;
      int idc = vd ? id : 0;
      const float* plane = x + (((n * 3 + ci) * 16 + idc) * 16384);
      #pragma unroll
      for (int kh = 0; kh < 4; kh++) {
        int ih = ih0 + kh;
        bool v = vd && ((unsigned)ih < 128u);
        int ihc = (unsigned)ih < 128u ? ih : 0;
        const float* rp = plane + ihc * 128 + 8 * g;
        float r[10];
        float4 A = ld4(rp);
        float4 B = ld4(rp + 4);
        float rl = rp[-1 * (int)gl];
        float rr = rp[gr ? 8 : 0];
        r[0] = (v && gl) ? rl : 0.0f;
        r[1] = v ? A.x : 0.0f; r[2] = v ? A.y : 0.0f;
        r[3] = v ? A.z : 0.0f; r[4] = v ? A.w : 0.0f;
        r[5] = v ? B.x : 0.0f; r[6] = v ? B.y : 0.0f;
        r[7] = v ? B.z : 0.0f; r[8] = v ? B.w : 0.0f;
        r[9] = (v && gr) ? rr : 0.0f;
        #pragma unroll
        for (int co = 0; co < 4; co++) {
          const float* wb = w + ((co * 3 + ci) * 4 + kd) * 16 + kh * 4;
          #pragma unroll
          for (int kw = 0; kw < 4; kw++) {
            float wv = wb[kw];
            #pragma unroll
            for (int m = 0; m < 4; m++)
              acc[co][m] += r[2 * m + kw] * wv;
          }
        }
      }
    }
  }
  #pragma unroll
  for (int co = 0; co < 4; co++) {
    float4 o;
    o.x = fmaxf(acc[co][0], 0.0f); o.y = fmaxf(acc[co][1], 0.0f);
    o.z = fmaxf(acc[co][2], 0.0f); o.w = fmaxf(acc[co][3], 0.0f);
    st4(y + ((n * 4 + co) * 8 + od) * 4096 + oh * 64 + 4 * g, o);
  }
}

// conv2: thread = 1 pos x 4 co. 512 blocks.
__global__ __launch_bounds__(256) void conv2_k(
    const float* __restrict__ y1, const float* __restrict__ w,
    const float* __restrict__ bias, float* __restrict__ y) {
  int idx = blockIdx.x * 256 + threadIdx.x;
  int ow = idx & 31;
  int oh = (idx >> 5) & 31;
  int od = (idx >> 10) & 3;
  int n = (idx >> 12) & 15;
  int cog = idx >> 16;
  float acc[4];
  #pragma unroll
  for (int co = 0; co < 4; co++) acc[co] = bias[cog * 4 + co];
  int id0 = 2 * od - 1, ih0 = 2 * oh - 1, iw0 = 2 * ow - 1;
  bool vh[4], vw[4];
  #pragma unroll
  for (int l = 0; l < 4; l++) {
    vh[l] = (unsigned)(ih0 + l) < 64u;
    vw[l] = (unsigned)(iw0 + l) < 64u;
  }
  #pragma unroll 1
  for (int ci = 0; ci < 4; ci++) {
    const float* ip = y1 + ((n * 4 + ci) * 8) * 4096;
    #pragma unroll
    for (int kd = 0; kd < 4; kd++) {
      int id = id0 + kd;
      bool vd = (unsigned)id < 8u;
      const float* pp = ip + id * 4096;
      float p[4][4];
      #pragma unroll
      for (int kh = 0; kh < 4; kh++)
        #pragma unroll
        for (int kw = 0; kw < 4; kw++)
          p[kh][kw] = (vd && vh[kh] && vw[kw]) ? pp[(ih0 + kh) * 64 + (iw0 + kw)] : 0.0f;
      #pragma unroll
      for (int co = 0; co < 4; co++) {
        const float* wp = w + (((cog * 4 + co) * 4 + ci) * 4 + kd) * 16;
        #pragma unroll
        for (int kh = 0; kh < 4; kh++)
          #pragma unroll
          for (int kw = 0; kw < 4; kw++)
            acc[co] += p[kh][kw] * wp[kh * 4 + kw];
      }
    }
  }
  #pragma unroll
  for (int co = 0; co < 4; co++)
    y[((n * 8 + cog * 4 + co) * 4 + od) * 1024 + oh * 32 + ow] = fmaxf(acc[co], 0.0f);
}

// conv4: thread = 1 pos x 4 co. 1024 blocks.  (verified R3 form, unfused)
__global__ __launch_bounds__(256) void conv4_k(
    const float* __restrict__ y2, const float* __restrict__ w,
    const float* __restrict__ bias, float* __restrict__ z) {
  int idx = blockIdx.x * 256 + threadIdx.x;
  int ow = idx & 31;
  int oh = (idx >> 5) & 31;
  int od = (idx >> 10) & 3;
  int n = (idx >> 12) & 15;
  int cog = idx >> 16;
  float acc[4];
  #pragma unroll
  for (int co = 0; co < 4; co++) acc[co] = bias[cog * 4 + co];
  bool vh[3], vw[3];
  #pragma unroll
  for (int l = 0; l < 3; l++) {
    vh[l] = (unsigned)(oh - 1 + l) < 32u;
    vw[l] = (unsigned)(ow - 1 + l) < 32u;
  }
  #pragma unroll 1
  for (int ci = 0; ci < 8; ci++) {
    const float* ip = y2 + ((n * 8 + ci) * 4) * 1024;
    #pragma unroll
    for (int kd = 0; kd < 3; kd++) {
      int id = od - 1 + kd;
      bool vd = (unsigned)id < 4u;
      const float* pp = ip + id * 1024;
      float p[3][3];
      #pragma unroll
      for (int kh = 0; kh < 3; kh++)
        #pragma unroll
        for (int kw = 0; kw < 3; kw++)
          p[kh][kw] = (vd && vh[kh] && vw[kw]) ? pp[(oh - 1 + kh) * 32 + (ow - 1 + kw)] : 0.0f;
      #pragma unroll
      for (int co = 0; co < 4; co++) {
        const float* wp = w + (((cog * 4 + co) * 8 + ci) * 3 + kd) * 9;
        #pragma unroll
        for (int kh = 0; kh < 3; kh++)
          #pragma unroll
          for (int kw = 0; kw < 3; kw++)
            acc[co] += p[kh][kw] * wp[kh * 3 + kw];
      }
    }
  }
  #pragma unroll
  for (int co = 0; co < 4; co++)
    z[((n * 16 + cog * 4 + co) * 4 + od) * 1024 + oh * 32 + ow] =
        fminf(fmaxf(acc[co], 0.0f), 6.0f);
}

// VQ (verified R3 form, unfused)
__global__ __launch_bounds__(256) void vq_k(
    const float* __restrict__ z, const float* __restrict__ emb,
    float* __restrict__ quant, float* __restrict__ codes_out,
    float* __restrict__ stats) {
  __shared__ float se[32 * 16];
  __shared__ float se2[32];
  __shared__ float shist[32];
  __shared__ float swred[4];
  int tid = threadIdx.x;
  for (int i = tid; i < 512; i += 256) {
    int r = i >> 4;
    float v = emb[i];
    if (r == 0) v = 0.0f;
    else if (r == 1) v = 6.0f;
    se[i] = v;
  }
  if (tid < 32) shist[tid] = 0.0f;
  __syncthreads();
  if (tid < 32) {
    float s = 0.0f;
    #pragma unroll
    for (int d = 0; d < 16; d++) { float v = se[tid * 16 + d]; s += v * v; }
    se2[tid] = s;
  }
  __syncthreads();

  int idx = blockIdx.x * 256 + tid;
  float lsum = 0.0f;
  {
    int w_ = idx & 31; int t = idx >> 5;
    int h_ = t & 31; t >>= 5;
    int d_ = t & 3;  int b_ = t >> 2;
    const float* zp = z + b_ * 65536 + d_ * 1024 + h_ * 32 + w_;
    float f[16];
    float f2 = 0.0f;
    #pragma unroll
    for (int c = 0; c < 16; c++) { float v = zp[c * 4096]; f[c] = v; f2 += v * v; }
    float best = 1e30f; int bi = 0;
    for (int e = 0; e < 32; e++) {
      float dot = 0.0f;
      #pragma unroll
      for (int c = 0; c < 16; c++) dot += f[c] * se[e * 16 + c];
      float d2 = f2 - 2.0f * dot + se2[e];
      if (d2 < best) { best = d2; bi = e; }
    }
    float* qp = quant + b_ * 65536 + d_ * 1024 + h_ * 32 + w_;
    #pragma unroll
    for (int c = 0; c < 16; c++) {
      float q = se[bi * 16 + c];
      qp[c * 4096] = q;
      float df = q - f[c];
      lsum += df * df;
    }
    codes_out[idx] = (float)bi;
    atomicAdd(&shist[bi], 1.0f);
  }
  for (int o = 32; o; o >>= 1) lsum += __shfl_down(lsum, o);
  if ((tid & 63) == 0) swred[tid >> 6] = lsum;
  __syncthreads();
  if (tid == 0) atomicAdd(&stats[0], swred[0] + swred[1] + swred[2] + swred[3]);
  if (tid < 32) {
    float h = shist[tid];
    if (h != 0.0f) atomicAdd(&stats[1 + tid], h);
  }
}

__global__ void init_stats_k(float* __restrict__ stats) {
  int tid = threadIdx.x;
  if (tid < 33) stats[tid] = 0.0f;
}

__global__ void fin_k(const float* __restrict__ stats,
                      const float* __restrict__ cluster_size,
                      float* __restrict__ out_loss, float* __restrict__ out_perp,
                      float* __restrict__ out_used) {
  int tid = threadIdx.x;
  float v = 0.0f;
  float used = 0.0f;
  if (tid < 32) {
    float p = stats[1 + tid] * (1.0f / 65536.0f);
    v = p * logf(p + 1e-10f);
    used = (cluster_size[tid] > 1e-5f) ? 1.0f : 0.0f;
  }
  for (int o = 16; o; o >>= 1) { v += __shfl_down(v, o); used += __shfl_down(used, o); }
  if (tid == 0) {
    *out_perp = expf(-v);
    *out_used = used * (1.0f / 32.0f);
    *out_loss = 0.25f * stats[0] * (1.0f / 1048576.0f);
  }
}

// ============ deconv1 v3 (strip, unchanged) ============
__global__ __launch_bounds__(256) void deconv1_k(
    const float* __restrict__ q, const float* __restrict__ w,
    const float* __restrict__ bias, float* __restrict__ d1) {
  int bid = blockIdx.x;
  int cog = bid & 1;
  int ph  = (bid >> 1) & 1;
  int od  = (bid >> 2) & 7;
  int n   = bid >> 5;
  int tid = threadIdx.x;
  int g   = tid & 7;
  int bl  = tid >> 3;
  bool glf = (g > 0), grf = (g < 7);

  int kd0 = (od + 1) & 1;
  int idtop = (od + 1 - kd0) >> 1;
  int kh0 = (ph + 1) & 1;
  int ihtop = bl + ph;

  float acc[4][8];
  #pragma unroll
  for (int co = 0; co < 4; co++) {
    float bv = bias[cog * 4 + co];
    #pragma unroll
    for (int m = 0; m < 8; m++) acc[co][m] = bv;
  }

  #pragma unroll 1
  for (int ci = 0; ci < 16; ci++) {
    const float* ip = q + ((n * 16 + ci) * 4) * 1024;
    #pragma unroll
    for (int jd = 0; jd < 2; jd++) {
      int id = idtop - jd;
      bool vd = (unsigned)id < 4u;
      int idc = vd ? id : 0;
      const float* plane = ip + idc * 1024;
      #pragma unroll
      for (int jh = 0; jh < 2; jh++) {
        int ih = ihtop - jh;
        bool v = vd && ((unsigned)ih < 32u);
        int ihc = (unsigned)ih < 32u ? ih : 0;
        const float* rp = plane + ihc * 32 + 4 * g;
        float r[6];
        float4 A = ld4(rp);
        float rl = rp[-1 * (int)glf];
        float rr = rp[grf ? 4 : 0];
        r[0] = (v && glf) ? rl : 0.0f;
        r[1] = v ? A.x : 0.0f; r[2] = v ? A.y : 0.0f;
        r[3] = v ? A.z : 0.0f; r[4] = v ? A.w : 0.0f;
        r[5] = (v && grf) ? rr : 0.0f;
        int kd = kd0 + 2 * jd;
        int kh = kh0 + 2 * jh;
        #pragma unroll
        for (int co = 0; co < 4; co++) {
          const float* wb = w + ((ci * 8 + cog * 4 + co) * 4 + kd) * 16 + kh * 4;
          #pragma unroll
          for (int jw = 0; jw < 2; jw++) {
            float w_ev = wb[1 + 2 * jw];
            float w_od = wb[2 * jw];
            #pragma unroll
            for (int ii = 0; ii < 4; ii++) {
              acc[co][2 * ii]     += r[ii + 1 - jw] * w_ev;
              acc[co][2 * ii + 1] += r[ii + 2 - jw] * w_od;
            }
          }
        }
      }
    }
  }
  int oh = 2 * bl + ph;
  #pragma unroll
  for (int co = 0; co < 4; co++) {
    float* op = d1 + ((n * 8 + cog * 4 + co) * 8 + od) * 4096 + oh * 64 + 8 * g;
    float4 lo, hi;
    lo.x = fmaxf(acc[co][0], 0.0f); lo.y = fmaxf(acc[co][1], 0.0f);
    lo.z = fmaxf(acc[co][2], 0.0f); lo.w = fmaxf(acc[co][3], 0.0f);
    hi.x = fmaxf(acc[co][4], 0.0f); hi.y = fmaxf(acc[co][5], 0.0f);
    hi.z = fmaxf(acc[co][6], 0.0f); hi.w = fmaxf(acc[co][7], 0.0f);
    st4(op, lo); st4(op + 4, hi);
  }
}

// ============ deconv3 strip — templated store target ============
// PADDED=0: legacy d2[n][co][16][128][128].  PADDED=1: d2p[n][co][18][130][136].
template <int PADDED>
__global__ __launch_bounds__(256) void deconv3_t(
    const float* __restrict__ d1, const float* __restrict__ w,
    const float* __restrict__ bias, float* __restrict__ d2) {
  int bid = blockIdx.x;
  int ph  = bid & 1;
  int blh = (bid >> 1) & 3;
  int od  = (bid >> 3) & 15;
  int n   = bid >> 7;
  int tid = threadIdx.x;
  int g   = tid & 15;
  int bl  = tid >> 4;
  int BL  = blh * 16 + bl;
  bool glf = (g > 0), grf = (g < 15);

  int kd0 = (od + 1) & 1;
  int idtop = (od + 1 - kd0) >> 1;
  int kh0 = (ph + 1) & 1;
  int ihtop = BL + ph;

  float acc[4][8];
  #pragma unroll
  for (int co = 0; co < 4; co++) {
    float bv = bias[co];
    #pragma unroll
    for (int m = 0; m < 8; m++) acc[co][m] = bv;
  }

  #pragma unroll 1
  for (int ci = 0; ci < 8; ci++) {
    const float* ip = d1 + ((n * 8 + ci) * 8) * 4096;
    #pragma unroll
    for (int jd = 0; jd < 2; jd++) {
      int id = idtop - jd;
      bool vd = (unsigned)id < 8u;
      int idc = vd ? id : 0;
      const float* plane = ip + idc * 4096;
      #pragma unroll
      for (int jh = 0; jh < 2; jh++) {
        int ih = ihtop - jh;
        bool v = vd && ((unsigned)ih < 64u);
        int ihc = (unsigned)ih < 64u ? ih : 0;
        const float* rp = plane + ihc * 64 + 4 * g;
        float r[6];
        float4 A = ld4(rp);
        float rl = rp[-1 * (int)glf];
        float rr = rp[grf ? 4 : 0];
        r[0] = (v && glf) ? rl : 0.0f;
        r[1] = v ? A.x : 0.0f; r[2] = v ? A.y : 0.0f;
        r[3] = v ? A.z : 0.0f; r[4] = v ? A.w : 0.0f;
        r[5] = (v && grf) ? rr : 0.0f;
        int kd = kd0 + 2 * jd;
        int kh = kh0 + 2 * jh;
        #pragma unroll
        for (int co = 0; co < 4; co++) {
          const float* wb = w + ((ci * 4 + co) * 4 + kd) * 16 + kh * 4;
          #pragma unroll
          for (int jw = 0; jw < 2; jw++) {
            float w_ev = wb[1 + 2 * jw];
            float w_od = wb[2 * jw];
            #pragma unroll
            for (int ii = 0; ii < 4; ii++) {
              acc[co][2 * ii]     += r[ii + 1 - jw] * w_ev;
              acc[co][2 * ii + 1] += r[ii + 2 - jw] * w_od;
            }
          }
        }
      }
    }
  }
  int oh = 2 * BL + ph;
  #pragma unroll
  for (int co = 0; co < 4; co++) {
    float* op;
    if (PADDED)
      op = d2 + (size_t)(n * 4 + co) * P_VOL + (od + 1) * P_PLANE + (oh + 1) * P_STRIDE + 8 * g + 4;
    else
      op = d2 + ((n * 4 + co) * 16 + od) * 16384 + oh * 128 + 8 * g;
    float4 lo, hi;
    lo.x = fmaxf(acc[co][0], 0.0f); lo.y = fmaxf(acc[co][1], 0.0f);
    lo.z = fmaxf(acc[co][2], 0.0f); lo.w = fmaxf(acc[co][3], 0.0f);
    hi.x = fmaxf(acc[co][4], 0.0f); hi.y = fmaxf(acc[co][5], 0.0f);
    hi.z = fmaxf(acc[co][6], 0.0f); hi.w = fmaxf(acc[co][7], 0.0f);
    st4(op, lo); st4(op + 4, hi);
  }
}

// zero the read-but-never-written halo of d2p (2.8M floats, ~3us)
__global__ __launch_bounds__(256) void zero_halo_k(float* __restrict__ d2p) {
  const int PER = 43808;  // 2*17680 + 16*272 + 16*256 per (n,ci)
  int total = PER * 64;
  for (int i = blockIdx.x * 256 + threadIdx.x; i < total; i += gridDim.x * 256) {
    int nc = i / PER;
    int j = i - nc * PER;
    int elem;
    if (j < 35360) {                       // full planes pd=0,17
      int pd = (j < 17680) ? 0 : 17;
      int off = (j < 17680) ? j : j - 17680;
      elem = pd * P_PLANE + off;
    } else if (j < 39712) {                // rows 0,129 of planes 1..16
      int k = j - 35360;
      int pd = 1 + (k / 272);
      int rj = k - (pd - 1) * 272;
      int row = (rj < 136) ? 0 : 129;
      int col = (rj < 136) ? rj : rj - 136;
      elem = pd * P_PLANE + row * P_STRIDE + col;
    } else {                               // cols 3,132 of rows 1..128, planes 1..16
      int k = j - 39712;
      int pd = 1 + (k / 256);
      int rj = k - (pd - 1) * 256;
      int row = 1 + (rj >> 1);
      int col = (rj & 1) ? 132 : 3;
      elem = pd * P_PLANE + row * P_STRIDE + col;
    }
    d2p[(size_t)nc * P_VOL + elem] = 0.0f;
  }
}

// ============ deconv4 cube, legacy (verified 78.6us) ============
__global__ __launch_bounds__(256) void deconv4_k(
    const float* __restrict__ d2, const float* __restrict__ w,
    const float* __restrict__ bias, float* __restrict__ out) {
  int idx = blockIdx.x * 256 + threadIdx.x;
  int c = idx & 63;
  int b = (idx >> 6) & 63;
  int a = (idx >> 12) & 7;
  int n = idx >> 15;
  float acc[2][2][2][3];
  #pragma unroll
  for (int pd = 0; pd < 2; pd++)
    #pragma unroll
    for (int ph = 0; ph < 2; ph++)
      #pragma unroll
      for (int pw = 0; pw < 2; pw++)
        #pragma unroll
        for (int co = 0; co < 3; co++) acc[pd][ph][pw][co] = bias[co];
  int ih0 = 2 * b - 1, iw0 = 2 * c - 1;
  bool vh[4], vw[4];
  #pragma unroll
  for (int l = 0; l < 4; l++) {
    vh[l] = (unsigned)(ih0 + l) < 128u;
    vw[l] = (unsigned)(iw0 + l) < 128u;
  }
  #pragma unroll 1
  for (int ci = 0; ci < 4; ci++) {
    const float* ip = d2 + ((n * 4 + ci) * 16) * 16384;
    #pragma unroll
    for (int ld = 0; ld < 4; ld++) {
      int id = 2 * a - 1 + ld;
      bool vdl = (unsigned)id < 16u;
      const float* pp = ip + id * 16384;
      float p[4][4];
      #pragma unroll
      for (int lh = 0; lh < 4; lh++)
        #pragma unroll
        for (int lw = 0; lw < 4; lw++)
          p[lh][lw] = (vdl && vh[lh] && vw[lw]) ? pp[(ih0 + lh) * 128 + (iw0 + lw)] : 0.0f;
      #pragma unroll
      for (int pd = 0; pd < 2; pd++) {
        int kd = pd + 2 - ld;
        if (kd < 0 || kd > 2) continue;
        #pragma unroll
        for (int kh = 0; kh < 3; kh++)
          #pragma unroll
          for (int kw = 0; kw < 3; kw++)
            #pragma unroll
            for (int co = 0; co < 3; co++) {
              float wv = w[(ci * 3 + co) * 27 + kd * 9 + kh * 3 + kw];
              #pragma unroll
              for (int ph = 0; ph < 2; ph++)
                #pragma unroll
                for (int pw = 0; pw < 2; pw++)
                  acc[pd][ph][pw][co] += p[ph + 2 - kh][pw + 2 - kw] * wv;
            }
      }
    }
  }
  #pragma unroll
  for (int co = 0; co < 3; co++)
    #pragma unroll
    for (int pd = 0; pd < 2; pd++)
      #pragma unroll
      for (int ph = 0; ph < 2; ph++)
        #pragma unroll
        for (int pw = 0; pw < 2; pw++)
          out[((n * 3 + co) * 16 + 2 * a + pd) * 16384 +
              (2 * b + ph) * 128 + (2 * c + pw)] = acc[pd][ph][pw][co];
}

// ============ deconv4 cube, padded input — NO predication ============
// Same cube/compute as verified deconv4_k; p[][] fill is unconditional
// constant-offset loads from d2p (halo pre-zeroed).
__global__ __launch_bounds__(256) void deconv4p_k(
    const float* __restrict__ d2p, const float* __restrict__ w,
    const float* __restrict__ bias, float* __restrict__ out) {
  int idx = blockIdx.x * 256 + threadIdx.x;
  int c = idx & 63;
  int b = (idx >> 6) & 63;
  int a = (idx >> 12) & 7;
  int n = idx >> 15;
  float acc[2][2][2][3];
  #pragma unroll
  for (int pd = 0; pd < 2; pd++)
    #pragma unroll
    for (int ph = 0; ph < 2; ph++)
      #pragma unroll
      for (int pw = 0; pw < 2; pw++)
        #pragma unroll
        for (int co = 0; co < 3; co++) acc[pd][ph][pw][co] = bias[co];
  #pragma unroll 1
  for (int ci = 0; ci < 4; ci++) {
    // base at (plane 2a, row 2b, col 2c+3): covers id=2a-1+ld, ih=2b-1+lh, iw=2c-1+lw
    const float* ip = d2p + (size_t)(n * 4 + ci) * P_VOL +
                      (2 * a) * P_PLANE + (2 * b) * P_STRIDE + (2 * c + 3);
    #pragma unroll
    for (int ld = 0; ld < 4; ld++) {
      const float* pp = ip + ld * P_PLANE;
      float p[4][4];
      #pragma unroll
      for (int lh = 0; lh < 4; lh++)
        #pragma unroll
        for (int lw = 0; lw < 4; lw++)
          p[lh][lw] = pp[lh * P_STRIDE + lw];
      #pragma unroll
      for (int pd = 0; pd < 2; pd++) {
        int kd = pd + 2 - ld;
        if (kd < 0 || kd > 2) continue;
        #pragma unroll
        for (int kh = 0; kh < 3; kh++)
          #pragma unroll
          for (int kw = 0; kw < 3; kw++)
            #pragma unroll
            for (int co = 0; co < 3; co++) {
              float wv = w[(ci * 3 + co) * 27 + kd * 9 + kh * 3 + kw];
              #pragma unroll
              for (int ph = 0; ph < 2; ph++)
                #pragma unroll
                for (int pw = 0; pw < 2; pw++)
                  acc[pd][ph][pw][co] += p[ph + 2 - kh][pw + 2 - kw] * wv;
            }
      }
    }
  }
  #pragma unroll
  for (int co = 0; co < 3; co++)
    #pragma unroll
    for (int pd = 0; pd < 2; pd++)
      #pragma unroll
      for (int ph = 0; ph < 2; ph++)
        #pragma unroll
        for (int pw = 0; pw < 2; pw++)
          out[((n * 3 + co) * 16 + 2 * a + pd) * 16384 +
              (2 * b + ph) * 128 + (2 * c + pw)] = acc[pd][ph][pw][co];
}

extern "C" void kernel_launch(void* const* d_in, const int* in_sizes, int n_in,
                              void* d_out, int out_size, void* d_ws, size_t ws_size,
                              hipStream_t stream) {
  const float* x      = (const float*)d_in[0];
  const float* enc_w1 = (const float*)d_in[2];
  const float* enc_b1 = (const float*)d_in[3];
  const float* enc_w2 = (const float*)d_in[4];
  const float* enc_b2 = (const float*)d_in[5];
  const float* enc_w4 = (const float*)d_in[6];
  const float* enc_b4 = (const float*)d_in[7];
  const float* dec_w1 = (const float*)d_in[8];
  const float* dec_b1 = (const float*)d_in[9];
  const float* dec_w3 = (const float*)d_in[10];
  const float* dec_b3 = (const float*)d_in[11];
  const float* dec_w4 = (const float*)d_in[12];
  const float* dec_b4 = (const float*)d_in[13];
  const float* emb    = (const float*)d_in[14];
  const float* csize  = (const float*)d_in[15];

  float* ws = (float*)d_ws;
  float* stats = ws;                      // 64
  float* quant = ws + 64;                 // 1,048,576
  float* z     = quant + 1048576;         // 1,048,576
  float* y2    = z + 1048576;             // 524,288
  float* y1    = y2 + 524288;             // 2,097,152 (dead after conv2)
  float* d1    = z;                       // 4,194,304 (reuses z/y2/y1 region)
  float* d2    = ws + 64 + 1048576 + 4194304;  // legacy: 16,777,216 | padded: 20,367,360

  float* out   = (float*)d_out;                        // 12,582,912
  float* out_loss  = out + 12582912;
  float* out_codes = out_loss + 1;                     // 65,536
  float* out_perp  = out_codes + 65536;
  float* out_used  = out_perp + 1;

  // padded path needs (64 + 1048576 + 4194304 + 20367360) floats = 102,441,216 B
  const size_t PAD_NEED = (size_t)(64 + 1048576 + 4194304 + 20367360) * sizeof(float);
  bool padded = (ws_size >= PAD_NEED);

  init_stats_k<<<1, 64, 0, stream>>>(stats);
  if (padded) zero_halo_k<<<1024, 256, 0, stream>>>(d2);

  conv1_k<<<512, 256, 0, stream>>>(x, enc_w1, enc_b1, y1);
  conv2_k<<<512, 256, 0, stream>>>(y1, enc_w2, enc_b2, y2);
  conv4_k<<<1024, 256, 0, stream>>>(y2, enc_w4, enc_b4, z);

  vq_k<<<256, 256, 0, stream>>>(z, emb, quant, out_codes, stats);
  fin_k<<<1, 64, 0, stream>>>(stats, csize, out_loss, out_perp, out_used);

  deconv1_k<<<512, 256, 0, stream>>>(quant, dec_w1, dec_b1, d1);
  if (padded) {
    deconv3_t<1><<<2048, 256, 0, stream>>>(d1, dec_w3, dec_b3, d2);
    deconv4p_k<<<2048, 256, 0, stream>>>(d2, dec_w4, dec_b4, out);
  } else {
    deconv3_t<0><<<2048, 256, 0, stream>>>(d1, dec_w3, dec_b3, d2);
    deconv4_k<<<2048, 256, 0, stream>>>(d2, dec_w4, dec_b4, out);
  }
}

// Round 8
// 357.703 us; speedup vs baseline: 1.1777x; 1.0057x over previous
//
#include <hip/hip_runtime.h>
#include <math.h>

#define NB 16

// ---------------- shapes ----------------
// x:      (16, 3,16,128,128)
// y1:     (16, 4, 8, 64, 64)   conv1 k4 s2 p1 + relu
// y2:     (16, 8, 4, 32, 32)   conv2 k4 s2 p1 + relu
// z:      (16,16, 4, 32, 32)   conv4 k3 s1 p1 + clip(0,6)
// quant:  (16,16, 4, 32, 32)   VQ
// d1:     (16, 8, 8, 64, 64)   deconv1 k4 s2 p1 + relu  (padded: [10][66][72])
// d2:     (16, 4,16,128,128)   deconv3 k4 s2 p1 + relu  (padded: [18][130][136])
// out:    (16, 3,16,128,128)   deconv4 k3 s1 p1

// padded d2 geometry
#define P_STRIDE 136              // col = iw + 4; st4 stays 16B-aligned
#define P_PLANE  (130 * P_STRIDE) // row = ih + 1
#define P_VOL    (18 * P_PLANE)   // plane = id + 1
// padded d1 geometry
#define D1_STRIDE 72              // col = iw + 4 (iw in -1..64 -> 3..68)
#define D1_PLANE  (66 * D1_STRIDE)  // 4752 ; row = ih + 1 (ih in -1..64 -> 0..65)
#define D1_VOL    (10 * D1_PLANE)   // 47520; plane = id + 1 (id in -1..8 -> 0..9)

__device__ __forceinline__ float4 ld4(const float* p) {
  return *reinterpret_cast<const float4*>(p);
}
__device__ __forceinline__ void st4(float* p, float4 v) {
  *reinterpret_cast<float4*>(p) = v;
}

// conv1 (R4 strip, measured fast): thread = 4 co x (1 od, 1 oh, 4 ow). 512 blocks.
__global__ __launch_bounds__(256) void conv1_k(
    const float* __restrict__ x, const float* __restrict__ w,
    const float* __restrict__ bias, float* __restrict__ y) {
  int idx = blockIdx.x * 256 + threadIdx.x;
  int g  = idx & 15;
  int oh = (idx >> 4) & 63;
  int od = (idx >> 10) & 7;
  int n  = idx >> 13;
  bool gl = (g > 0), gr = (g < 15);
  float acc[4][4];
  #pragma unroll
  for (int co = 0; co < 4; co++) {
    float bv = bias[co];
    #pragma unroll
    for (int m = 0; m < 4; m++) acc[co][m] = bv;
  }
  int ih0 = 2 * oh - 1;
  #pragma unroll 1
  for (int ci = 0; ci < 3; ci++) {
    #pragma unroll 1
    for (int kd = 0; kd < 4; kd++) {
      int id = 2 * od - 1 + kd;
      bool vd = (unsigned)id < 16u;
      int idc = vd ? id : 0;
      const float* plane = x + (((n * 3 + ci) * 16 + idc) * 16384);
      #pragma unroll
      for (int kh = 0; kh < 4; kh++) {
        int ih = ih0 + kh;
        bool v = vd && ((unsigned)ih < 128u);
        int ihc = (unsigned)ih < 128u ? ih : 0;
        const float* rp = plane + ihc * 128 + 8 * g;
        float r[10];
        float4 A = ld4(rp);
        float4 B = ld4(rp + 4);
        float rl = rp[-1 * (int)gl];
        float rr = rp[gr ? 8 : 0];
        r[0] = (v && gl) ? rl : 0.0f;
        r[1] = v ? A.x : 0.0f; r[2] = v ? A.y : 0.0f;
        r[3] = v ? A.z : 0.0f; r[4] = v ? A.w : 0.0f;
        r[5] = v ? B.x : 0.0f; r[6] = v ? B.y : 0.0f;
        r[7] = v ? B.z : 0.0f; r[8] = v ? B.w : 0.0f;
        r[9] = (v && gr) ? rr : 0.0f;
        #pragma unroll
        for (int co = 0; co < 4; co++) {
          const float* wb = w + ((co * 3 + ci) * 4 + kd) * 16 + kh * 4;
          #pragma unroll
          for (int kw = 0; kw < 4; kw++) {
            float wv = wb[kw];
            #pragma unroll
            for (int m = 0; m < 4; m++)
              acc[co][m] += r[2 * m + kw] * wv;
          }
        }
      }
    }
  }
  #pragma unroll
  for (int co = 0; co < 4; co++) {
    float4 o;
    o.x = fmaxf(acc[co][0], 0.0f); o.y = fmaxf(acc[co][1], 0.0f);
    o.z = fmaxf(acc[co][2], 0.0f); o.w = fmaxf(acc[co][3], 0.0f);
    st4(y + ((n * 4 + co) * 8 + od) * 4096 + oh * 64 + 4 * g, o);
  }
}

// conv2: thread = 1 pos x 4 co. 512 blocks.
__global__ __launch_bounds__(256) void conv2_k(
    const float* __restrict__ y1, const float* __restrict__ w,
    const float* __restrict__ bias, float* __restrict__ y) {
  int idx = blockIdx.x * 256 + threadIdx.x;
  int ow = idx & 31;
  int oh = (idx >> 5) & 31;
  int od = (idx >> 10) & 3;
  int n = (idx >> 12) & 15;
  int cog = idx >> 16;
  float acc[4];
  #pragma unroll
  for (int co = 0; co < 4; co++) acc[co] = bias[cog * 4 + co];
  int id0 = 2 * od - 1, ih0 = 2 * oh - 1, iw0 = 2 * ow - 1;
  bool vh[4], vw[4];
  #pragma unroll
  for (int l = 0; l < 4; l++) {
    vh[l] = (unsigned)(ih0 + l) < 64u;
    vw[l] = (unsigned)(iw0 + l) < 64u;
  }
  #pragma unroll 1
  for (int ci = 0; ci < 4; ci++) {
    const float* ip = y1 + ((n * 4 + ci) * 8) * 4096;
    #pragma unroll
    for (int kd = 0; kd < 4; kd++) {
      int id = id0 + kd;
      bool vd = (unsigned)id < 8u;
      const float* pp = ip + id * 4096;
      float p[4][4];
      #pragma unroll
      for (int kh = 0; kh < 4; kh++)
        #pragma unroll
        for (int kw = 0; kw < 4; kw++)
          p[kh][kw] = (vd && vh[kh] && vw[kw]) ? pp[(ih0 + kh) * 64 + (iw0 + kw)] : 0.0f;
      #pragma unroll
      for (int co = 0; co < 4; co++) {
        const float* wp = w + (((cog * 4 + co) * 4 + ci) * 4 + kd) * 16;
        #pragma unroll
        for (int kh = 0; kh < 4; kh++)
          #pragma unroll
          for (int kw = 0; kw < 4; kw++)
            acc[co] += p[kh][kw] * wp[kh * 4 + kw];
      }
    }
  }
  #pragma unroll
  for (int co = 0; co < 4; co++)
    y[((n * 8 + cog * 4 + co) * 4 + od) * 1024 + oh * 32 + ow] = fmaxf(acc[co], 0.0f);
}

// conv4: thread = 1 pos x 4 co. 1024 blocks.
__global__ __launch_bounds__(256) void conv4_k(
    const float* __restrict__ y2, const float* __restrict__ w,
    const float* __restrict__ bias, float* __restrict__ z) {
  int idx = blockIdx.x * 256 + threadIdx.x;
  int ow = idx & 31;
  int oh = (idx >> 5) & 31;
  int od = (idx >> 10) & 3;
  int n = (idx >> 12) & 15;
  int cog = idx >> 16;
  float acc[4];
  #pragma unroll
  for (int co = 0; co < 4; co++) acc[co] = bias[cog * 4 + co];
  bool vh[3], vw[3];
  #pragma unroll
  for (int l = 0; l < 3; l++) {
    vh[l] = (unsigned)(oh - 1 + l) < 32u;
    vw[l] = (unsigned)(ow - 1 + l) < 32u;
  }
  #pragma unroll 1
  for (int ci = 0; ci < 8; ci++) {
    const float* ip = y2 + ((n * 8 + ci) * 4) * 1024;
    #pragma unroll
    for (int kd = 0; kd < 3; kd++) {
      int id = od - 1 + kd;
      bool vd = (unsigned)id < 4u;
      const float* pp = ip + id * 1024;
      float p[3][3];
      #pragma unroll
      for (int kh = 0; kh < 3; kh++)
        #pragma unroll
        for (int kw = 0; kw < 3; kw++)
          p[kh][kw] = (vd && vh[kh] && vw[kw]) ? pp[(oh - 1 + kh) * 32 + (ow - 1 + kw)] : 0.0f;
      #pragma unroll
      for (int co = 0; co < 4; co++) {
        const float* wp = w + (((cog * 4 + co) * 8 + ci) * 3 + kd) * 9;
        #pragma unroll
        for (int kh = 0; kh < 3; kh++)
          #pragma unroll
          for (int kw = 0; kw < 3; kw++)
            acc[co] += p[kh][kw] * wp[kh * 3 + kw];
      }
    }
  }
  #pragma unroll
  for (int co = 0; co < 4; co++)
    z[((n * 16 + cog * 4 + co) * 4 + od) * 1024 + oh * 32 + ow] =
        fminf(fmaxf(acc[co], 0.0f), 6.0f);
}

// VQ (verified)
__global__ __launch_bounds__(256) void vq_k(
    const float* __restrict__ z, const float* __restrict__ emb,
    float* __restrict__ quant, float* __restrict__ codes_out,
    float* __restrict__ stats) {
  __shared__ float se[32 * 16];
  __shared__ float se2[32];
  __shared__ float shist[32];
  __shared__ float swred[4];
  int tid = threadIdx.x;
  for (int i = tid; i < 512; i += 256) {
    int r = i >> 4;
    float v = emb[i];
    if (r == 0) v = 0.0f;
    else if (r == 1) v = 6.0f;
    se[i] = v;
  }
  if (tid < 32) shist[tid] = 0.0f;
  __syncthreads();
  if (tid < 32) {
    float s = 0.0f;
    #pragma unroll
    for (int d = 0; d < 16; d++) { float v = se[tid * 16 + d]; s += v * v; }
    se2[tid] = s;
  }
  __syncthreads();

  int idx = blockIdx.x * 256 + tid;
  float lsum = 0.0f;
  {
    int w_ = idx & 31; int t = idx >> 5;
    int h_ = t & 31; t >>= 5;
    int d_ = t & 3;  int b_ = t >> 2;
    const float* zp = z + b_ * 65536 + d_ * 1024 + h_ * 32 + w_;
    float f[16];
    float f2 = 0.0f;
    #pragma unroll
    for (int c = 0; c < 16; c++) { float v = zp[c * 4096]; f[c] = v; f2 += v * v; }
    float best = 1e30f; int bi = 0;
    for (int e = 0; e < 32; e++) {
      float dot = 0.0f;
      #pragma unroll
      for (int c = 0; c < 16; c++) dot += f[c] * se[e * 16 + c];
      float d2 = f2 - 2.0f * dot + se2[e];
      if (d2 < best) { best = d2; bi = e; }
    }
    float* qp = quant + b_ * 65536 + d_ * 1024 + h_ * 32 + w_;
    #pragma unroll
    for (int c = 0; c < 16; c++) {
      float q = se[bi * 16 + c];
      qp[c * 4096] = q;
      float df = q - f[c];
      lsum += df * df;
    }
    codes_out[idx] = (float)bi;
    atomicAdd(&shist[bi], 1.0f);
  }
  for (int o = 32; o; o >>= 1) lsum += __shfl_down(lsum, o);
  if ((tid & 63) == 0) swred[tid >> 6] = lsum;
  __syncthreads();
  if (tid == 0) atomicAdd(&stats[0], swred[0] + swred[1] + swred[2] + swred[3]);
  if (tid < 32) {
    float h = shist[tid];
    if (h != 0.0f) atomicAdd(&stats[1 + tid], h);
  }
}

__global__ void init_stats_k(float* __restrict__ stats) {
  int tid = threadIdx.x;
  if (tid < 33) stats[tid] = 0.0f;
}

__global__ void fin_k(const float* __restrict__ stats,
                      const float* __restrict__ cluster_size,
                      float* __restrict__ out_loss, float* __restrict__ out_perp,
                      float* __restrict__ out_used) {
  int tid = threadIdx.x;
  float v = 0.0f;
  float used = 0.0f;
  if (tid < 32) {
    float p = stats[1 + tid] * (1.0f / 65536.0f);
    v = p * logf(p + 1e-10f);
    used = (cluster_size[tid] > 1e-5f) ? 1.0f : 0.0f;
  }
  for (int o = 16; o; o >>= 1) { v += __shfl_down(v, o); used += __shfl_down(used, o); }
  if (tid == 0) {
    *out_perp = expf(-v);
    *out_used = used * (1.0f / 32.0f);
    *out_loss = 0.25f * stats[0] * (1.0f / 1048576.0f);
  }
}

// ============ deconv1 strip — templated store target ============
// PADDED=0: legacy d1[n][c][8][64][64]. PADDED=1: d1p[n][c][10][66][72].
template <int PADDED>
__global__ __launch_bounds__(256) void deconv1_t(
    const float* __restrict__ q, const float* __restrict__ w,
    const float* __restrict__ bias, float* __restrict__ d1) {
  int bid = blockIdx.x;
  int cog = bid & 1;
  int ph  = (bid >> 1) & 1;
  int od  = (bid >> 2) & 7;
  int n   = bid >> 5;
  int tid = threadIdx.x;
  int g   = tid & 7;
  int bl  = tid >> 3;
  bool glf = (g > 0), grf = (g < 7);

  int kd0 = (od + 1) & 1;
  int idtop = (od + 1 - kd0) >> 1;
  int kh0 = (ph + 1) & 1;
  int ihtop = bl + ph;

  float acc[4][8];
  #pragma unroll
  for (int co = 0; co < 4; co++) {
    float bv = bias[cog * 4 + co];
    #pragma unroll
    for (int m = 0; m < 8; m++) acc[co][m] = bv;
  }

  #pragma unroll 1
  for (int ci = 0; ci < 16; ci++) {
    const float* ip = q + ((n * 16 + ci) * 4) * 1024;
    #pragma unroll
    for (int jd = 0; jd < 2; jd++) {
      int id = idtop - jd;
      bool vd = (unsigned)id < 4u;
      int idc = vd ? id : 0;
      const float* plane = ip + idc * 1024;
      #pragma unroll
      for (int jh = 0; jh < 2; jh++) {
        int ih = ihtop - jh;
        bool v = vd && ((unsigned)ih < 32u);
        int ihc = (unsigned)ih < 32u ? ih : 0;
        const float* rp = plane + ihc * 32 + 4 * g;
        float r[6];
        float4 A = ld4(rp);
        float rl = rp[-1 * (int)glf];
        float rr = rp[grf ? 4 : 0];
        r[0] = (v && glf) ? rl : 0.0f;
        r[1] = v ? A.x : 0.0f; r[2] = v ? A.y : 0.0f;
        r[3] = v ? A.z : 0.0f; r[4] = v ? A.w : 0.0f;
        r[5] = (v && grf) ? rr : 0.0f;
        int kd = kd0 + 2 * jd;
        int kh = kh0 + 2 * jh;
        #pragma unroll
        for (int co = 0; co < 4; co++) {
          const float* wb = w + ((ci * 8 + cog * 4 + co) * 4 + kd) * 16 + kh * 4;
          #pragma unroll
          for (int jw = 0; jw < 2; jw++) {
            float w_ev = wb[1 + 2 * jw];
            float w_od = wb[2 * jw];
            #pragma unroll
            for (int ii = 0; ii < 4; ii++) {
              acc[co][2 * ii]     += r[ii + 1 - jw] * w_ev;
              acc[co][2 * ii + 1] += r[ii + 2 - jw] * w_od;
            }
          }
        }
      }
    }
  }
  int oh = 2 * bl + ph;
  #pragma unroll
  for (int co = 0; co < 4; co++) {
    float* op;
    if (PADDED)
      op = d1 + (size_t)(n * 8 + cog * 4 + co) * D1_VOL +
           (od + 1) * D1_PLANE + (oh + 1) * D1_STRIDE + 8 * g + 4;
    else
      op = d1 + ((n * 8 + cog * 4 + co) * 8 + od) * 4096 + oh * 64 + 8 * g;
    float4 lo, hi;
    lo.x = fmaxf(acc[co][0], 0.0f); lo.y = fmaxf(acc[co][1], 0.0f);
    lo.z = fmaxf(acc[co][2], 0.0f); lo.w = fmaxf(acc[co][3], 0.0f);
    hi.x = fmaxf(acc[co][4], 0.0f); hi.y = fmaxf(acc[co][5], 0.0f);
    hi.z = fmaxf(acc[co][6], 0.0f); hi.w = fmaxf(acc[co][7], 0.0f);
    st4(op, lo); st4(op + 4, hi);
  }
}

// ============ deconv3 strip — templated input (d1) and output (d2) ============
// INP=1: unconditional loads from padded d1p. OUTP=1: padded d2p stores.
template <int INP, int OUTP>
__global__ __launch_bounds__(256) void deconv3_t(
    const float* __restrict__ d1, const float* __restrict__ w,
    const float* __restrict__ bias, float* __restrict__ d2) {
  int bid = blockIdx.x;
  int ph  = bid & 1;
  int blh = (bid >> 1) & 3;
  int od  = (bid >> 3) & 15;
  int n   = bid >> 7;
  int tid = threadIdx.x;
  int g   = tid & 15;
  int bl  = tid >> 4;
  int BL  = blh * 16 + bl;
  bool glf = (g > 0), grf = (g < 15);

  int kd0 = (od + 1) & 1;
  int idtop = (od + 1 - kd0) >> 1;
  int kh0 = (ph + 1) & 1;
  int ihtop = BL + ph;

  float acc[4][8];
  #pragma unroll
  for (int co = 0; co < 4; co++) {
    float bv = bias[co];
    #pragma unroll
    for (int m = 0; m < 8; m++) acc[co][m] = bv;
  }

  #pragma unroll 1
  for (int ci = 0; ci < 8; ci++) {
    #pragma unroll
    for (int jd = 0; jd < 2; jd++) {
      #pragma unroll
      for (int jh = 0; jh < 2; jh++) {
        float r[6];
        if (INP) {
          // padded: base at (plane idtop+1-jd, row ihtop+1-jh, col 4g+4); halo pre-zeroed
          const float* rp = d1 + (size_t)(n * 8 + ci) * D1_VOL +
                            (idtop + 1 - jd) * D1_PLANE + (ihtop + 1 - jh) * D1_STRIDE +
                            4 * g + 4;
          float4 A = ld4(rp);
          r[0] = rp[-1];
          r[1] = A.x; r[2] = A.y; r[3] = A.z; r[4] = A.w;
          r[5] = rp[4];
        } else {
          const float* ip = d1 + ((n * 8 + ci) * 8) * 4096;
          int id = idtop - jd;
          bool vd = (unsigned)id < 8u;
          int idc = vd ? id : 0;
          const float* plane = ip + idc * 4096;
          int ih = ihtop - jh;
          bool v = vd && ((unsigned)ih < 64u);
          int ihc = (unsigned)ih < 64u ? ih : 0;
          const float* rp = plane + ihc * 64 + 4 * g;
          float4 A = ld4(rp);
          float rl = rp[-1 * (int)glf];
          float rr = rp[grf ? 4 : 0];
          r[0] = (v && glf) ? rl : 0.0f;
          r[1] = v ? A.x : 0.0f; r[2] = v ? A.y : 0.0f;
          r[3] = v ? A.z : 0.0f; r[4] = v ? A.w : 0.0f;
          r[5] = (v && grf) ? rr : 0.0f;
        }
        int kd = kd0 + 2 * jd;
        int kh = kh0 + 2 * jh;
        #pragma unroll
        for (int co = 0; co < 4; co++) {
          const float* wb = w + ((ci * 4 + co) * 4 + kd) * 16 + kh * 4;
          #pragma unroll
          for (int jw = 0; jw < 2; jw++) {
            float w_ev = wb[1 + 2 * jw];
            float w_od = wb[2 * jw];
            #pragma unroll
            for (int ii = 0; ii < 4; ii++) {
              acc[co][2 * ii]     += r[ii + 1 - jw] * w_ev;
              acc[co][2 * ii + 1] += r[ii + 2 - jw] * w_od;
            }
          }
        }
      }
    }
  }
  int oh = 2 * BL + ph;
  #pragma unroll
  for (int co = 0; co < 4; co++) {
    float* op;
    if (OUTP)
      op = d2 + (size_t)(n * 4 + co) * P_VOL + (od + 1) * P_PLANE + (oh + 1) * P_STRIDE + 8 * g + 4;
    else
      op = d2 + ((n * 4 + co) * 16 + od) * 16384 + oh * 128 + 8 * g;
    float4 lo, hi;
    lo.x = fmaxf(acc[co][0], 0.0f); lo.y = fmaxf(acc[co][1], 0.0f);
    lo.z = fmaxf(acc[co][2], 0.0f); lo.w = fmaxf(acc[co][3], 0.0f);
    hi.x = fmaxf(acc[co][4], 0.0f); hi.y = fmaxf(acc[co][5], 0.0f);
    hi.z = fmaxf(acc[co][6], 0.0f); hi.w = fmaxf(acc[co][7], 0.0f);
    st4(op, lo); st4(op + 4, hi);
  }
}

// zero the read-but-never-written halo of d2p
__global__ __launch_bounds__(256) void zero_halo_k(float* __restrict__ d2p) {
  const int PER = 43808;
  int total = PER * 64;
  for (int i = blockIdx.x * 256 + threadIdx.x; i < total; i += gridDim.x * 256) {
    int nc = i / PER;
    int j = i - nc * PER;
    int elem;
    if (j < 35360) {
      int pd = (j < 17680) ? 0 : 17;
      int off = (j < 17680) ? j : j - 17680;
      elem = pd * P_PLANE + off;
    } else if (j < 39712) {
      int k = j - 35360;
      int pd = 1 + (k / 272);
      int rj = k - (pd - 1) * 272;
      int row = (rj < 136) ? 0 : 129;
      int col = (rj < 136) ? rj : rj - 136;
      elem = pd * P_PLANE + row * P_STRIDE + col;
    } else {
      int k = j - 39712;
      int pd = 1 + (k / 256);
      int rj = k - (pd - 1) * 256;
      int row = 1 + (rj >> 1);
      int col = (rj & 1) ? 132 : 3;
      elem = pd * P_PLANE + row * P_STRIDE + col;
    }
    d2p[(size_t)nc * P_VOL + elem] = 0.0f;
  }
}

// zero the read-but-never-written halo of d1p (runs AFTER vq_k: overlaps dead z/y1/y2)
__global__ __launch_bounds__(256) void zero_halo_d1p_k(float* __restrict__ d1p) {
  const int PER = 11680;  // 2*4752 + 8*2*72 + 8*64*2 per (n,c)
  int total = PER * 128;
  for (int i = blockIdx.x * 256 + threadIdx.x; i < total; i += gridDim.x * 256) {
    int nc = i / PER;
    int j = i - nc * PER;
    int elem;
    if (j < 9504) {                        // full planes pd=0,9
      int pd = (j < 4752) ? 0 : 9;
      int off = (j < 4752) ? j : j - 4752;
      elem = pd * D1_PLANE + off;
    } else if (j < 10656) {                // rows 0,65 of planes 1..8
      int k = j - 9504;
      int pd = 1 + (k / 144);
      int rj = k - (pd - 1) * 144;
      int row = (rj < 72) ? 0 : 65;
      int col = (rj < 72) ? rj : rj - 72;
      elem = pd * D1_PLANE + row * D1_STRIDE + col;
    } else {                               // cols 3,68 of rows 1..64, planes 1..8
      int k = j - 10656;
      int pd = 1 + (k / 128);
      int rj = k - (pd - 1) * 128;
      int row = 1 + (rj >> 1);
      int col = (rj & 1) ? 68 : 3;
      elem = pd * D1_PLANE + row * D1_STRIDE + col;
    }
    d1p[(size_t)nc * D1_VOL + elem] = 0.0f;
  }
}

// ============ deconv4 cube, legacy (verified 78.6us) ============
__global__ __launch_bounds__(256) void deconv4_k(
    const float* __restrict__ d2, const float* __restrict__ w,
    const float* __restrict__ bias, float* __restrict__ out) {
  int idx = blockIdx.x * 256 + threadIdx.x;
  int c = idx & 63;
  int b = (idx >> 6) & 63;
  int a = (idx >> 12) & 7;
  int n = idx >> 15;
  float acc[2][2][2][3];
  #pragma unroll
  for (int pd = 0; pd < 2; pd++)
    #pragma unroll
    for (int ph = 0; ph < 2; ph++)
      #pragma unroll
      for (int pw = 0; pw < 2; pw++)
        #pragma unroll
        for (int co = 0; co < 3; co++) acc[pd][ph][pw][co] = bias[co];
  int ih0 = 2 * b - 1, iw0 = 2 * c - 1;
  bool vh[4], vw[4];
  #pragma unroll
  for (int l = 0; l < 4; l++) {
    vh[l] = (unsigned)(ih0 + l) < 128u;
    vw[l] = (unsigned)(iw0 + l) < 128u;
  }
  #pragma unroll 1
  for (int ci = 0; ci < 4; ci++) {
    const float* ip = d2 + ((n * 4 + ci) * 16) * 16384;
    #pragma unroll
    for (int ld = 0; ld < 4; ld++) {
      int id = 2 * a - 1 + ld;
      bool vdl = (unsigned)id < 16u;
      const float* pp = ip + id * 16384;
      float p[4][4];
      #pragma unroll
      for (int lh = 0; lh < 4; lh++)
        #pragma unroll
        for (int lw = 0; lw < 4; lw++)
          p[lh][lw] = (vdl && vh[lh] && vw[lw]) ? pp[(ih0 + lh) * 128 + (iw0 + lw)] : 0.0f;
      #pragma unroll
      for (int pd = 0; pd < 2; pd++) {
        int kd = pd + 2 - ld;
        if (kd < 0 || kd > 2) continue;
        #pragma unroll
        for (int kh = 0; kh < 3; kh++)
          #pragma unroll
          for (int kw = 0; kw < 3; kw++)
            #pragma unroll
            for (int co = 0; co < 3; co++) {
              float wv = w[(ci * 3 + co) * 27 + kd * 9 + kh * 3 + kw];
              #pragma unroll
              for (int ph = 0; ph < 2; ph++)
                #pragma unroll
                for (int pw = 0; pw < 2; pw++)
                  acc[pd][ph][pw][co] += p[ph + 2 - kh][pw + 2 - kw] * wv;
            }
      }
    }
  }
  #pragma unroll
  for (int co = 0; co < 3; co++)
    #pragma unroll
    for (int pd = 0; pd < 2; pd++)
      #pragma unroll
      for (int ph = 0; ph < 2; ph++)
        #pragma unroll
        for (int pw = 0; pw < 2; pw++)
          out[((n * 3 + co) * 16 + 2 * a + pd) * 16384 +
              (2 * b + ph) * 128 + (2 * c + pw)] = acc[pd][ph][pw][co];
}

// ============ deconv4 cube, padded input — NO predication (verified R7) ============
__global__ __launch_bounds__(256) void deconv4p_k(
    const float* __restrict__ d2p, const float* __restrict__ w,
    const float* __restrict__ bias, float* __restrict__ out) {
  int idx = blockIdx.x * 256 + threadIdx.x;
  int c = idx & 63;
  int b = (idx >> 6) & 63;
  int a = (idx >> 12) & 7;
  int n = idx >> 15;
  float acc[2][2][2][3];
  #pragma unroll
  for (int pd = 0; pd < 2; pd++)
    #pragma unroll
    for (int ph = 0; ph < 2; ph++)
      #pragma unroll
      for (int pw = 0; pw < 2; pw++)
        #pragma unroll
        for (int co = 0; co < 3; co++) acc[pd][ph][pw][co] = bias[co];
  #pragma unroll 1
  for (int ci = 0; ci < 4; ci++) {
    const float* ip = d2p + (size_t)(n * 4 + ci) * P_VOL +
                      (2 * a) * P_PLANE + (2 * b) * P_STRIDE + (2 * c + 3);
    #pragma unroll
    for (int ld = 0; ld < 4; ld++) {
      const float* pp = ip + ld * P_PLANE;
      float p[4][4];
      #pragma unroll
      for (int lh = 0; lh < 4; lh++)
        #pragma unroll
        for (int lw = 0; lw < 4; lw++)
          p[lh][lw] = pp[lh * P_STRIDE + lw];
      #pragma unroll
      for (int pd = 0; pd < 2; pd++) {
        int kd = pd + 2 - ld;
        if (kd < 0 || kd > 2) continue;
        #pragma unroll
        for (int kh = 0; kh < 3; kh++)
          #pragma unroll
          for (int kw = 0; kw < 3; kw++)
            #pragma unroll
            for (int co = 0; co < 3; co++) {
              float wv = w[(ci * 3 + co) * 27 + kd * 9 + kh * 3 + kw];
              #pragma unroll
              for (int ph = 0; ph < 2; ph++)
                #pragma unroll
                for (int pw = 0; pw < 2; pw++)
                  acc[pd][ph][pw][co] += p[ph + 2 - kh][pw + 2 - kw] * wv;
            }
      }
    }
  }
  #pragma unroll
  for (int co = 0; co < 3; co++)
    #pragma unroll
    for (int pd = 0; pd < 2; pd++)
      #pragma unroll
      for (int ph = 0; ph < 2; ph++)
        #pragma unroll
        for (int pw = 0; pw < 2; pw++)
          out[((n * 3 + co) * 16 + 2 * a + pd) * 16384 +
              (2 * b + ph) * 128 + (2 * c + pw)] = acc[pd][ph][pw][co];
}

extern "C" void kernel_launch(void* const* d_in, const int* in_sizes, int n_in,
                              void* d_out, int out_size, void* d_ws, size_t ws_size,
                              hipStream_t stream) {
  const float* x      = (const float*)d_in[0];
  const float* enc_w1 = (const float*)d_in[2];
  const float* enc_b1 = (const float*)d_in[3];
  const float* enc_w2 = (const float*)d_in[4];
  const float* enc_b2 = (const float*)d_in[5];
  const float* enc_w4 = (const float*)d_in[6];
  const float* enc_b4 = (const float*)d_in[7];
  const float* dec_w1 = (const float*)d_in[8];
  const float* dec_b1 = (const float*)d_in[9];
  const float* dec_w3 = (const float*)d_in[10];
  const float* dec_b3 = (const float*)d_in[11];
  const float* dec_w4 = (const float*)d_in[12];
  const float* dec_b4 = (const float*)d_in[13];
  const float* emb    = (const float*)d_in[14];
  const float* csize  = (const float*)d_in[15];

  float* ws = (float*)d_ws;
  float* stats = ws;                      // 64
  float* quant = ws + 64;                 // 1,048,576
  float* z     = quant + 1048576;         // 1,048,576
  float* y2    = z + 1048576;             // 524,288
  float* y1    = y2 + 524288;             // 2,097,152 (dead after conv2)

  float* out   = (float*)d_out;                        // 12,582,912
  float* out_loss  = out + 12582912;
  float* out_codes = out_loss + 1;                     // 65,536
  float* out_perp  = out_codes + 65536;
  float* out_used  = out_perp + 1;

  // Tier A (full pad): d1p at z (6,082,560), d2p after (20,367,360)
  const size_t FULL_NEED = (size_t)(64 + 1048576 + 6082560 + 20367360) * sizeof(float);
  // Tier B (R7): legacy d1 at z (4,194,304), d2p after
  const size_t MID_NEED  = (size_t)(64 + 1048576 + 4194304 + 20367360) * sizeof(float);

  init_stats_k<<<1, 64, 0, stream>>>(stats);

  conv1_k<<<512, 256, 0, stream>>>(x, enc_w1, enc_b1, y1);
  conv2_k<<<512, 256, 0, stream>>>(y1, enc_w2, enc_b2, y2);
  conv4_k<<<1024, 256, 0, stream>>>(y2, enc_w4, enc_b4, z);

  vq_k<<<256, 256, 0, stream>>>(z, emb, quant, out_codes, stats);
  fin_k<<<1, 64, 0, stream>>>(stats, csize, out_loss, out_perp, out_used);

  if (ws_size >= FULL_NEED) {
    float* d1p = ws + 64 + 1048576;                  // overlaps dead z/y2/y1
    float* d2p = d1p + 6082560;
    zero_halo_k<<<1024, 256, 0, stream>>>(d2p);      // d2p region untouched by encoder
    zero_halo_d1p_k<<<1024, 256, 0, stream>>>(d1p);  // after vq_k: z now dead
    deconv1_t<1><<<512, 256, 0, stream>>>(quant, dec_w1, dec_b1, d1p);
    deconv3_t<1, 1><<<2048, 256, 0, stream>>>(d1p, dec_w3, dec_b3, d2p);
    deconv4p_k<<<2048, 256, 0, stream>>>(d2p, dec_w4, dec_b4, out);
  } else if (ws_size >= MID_NEED) {
    float* d1  = ws + 64 + 1048576;
    float* d2p = d1 + 4194304;
    zero_halo_k<<<1024, 256, 0, stream>>>(d2p);
    deconv1_t<0><<<512, 256, 0, stream>>>(quant, dec_w1, dec_b1, d1);
    deconv3_t<0, 1><<<2048, 256, 0, stream>>>(d1, dec_w3, dec_b3, d2p);
    deconv4p_k<<<2048, 256, 0, stream>>>(d2p, dec_w4, dec_b4, out);
  } else {
    float* d1 = ws + 64 + 1048576;
    float* d2 = d1 + 4194304;
    deconv1_t<0><<<512, 256, 0, stream>>>(quant, dec_w1, dec_b1, d1);
    deconv3_t<0, 0><<<2048, 256, 0, stream>>>(d1, dec_w3, dec_b3, d2);
    deconv4_k<<<2048, 256, 0, stream>>>(d2, dec_w4, dec_b4, out);
  }
}

// Round 9
// 349.039 us; speedup vs baseline: 1.2069x; 1.0248x over previous
//
#include <hip/hip_runtime.h>
#include <math.h>

#define NB 16

// ---------------- shapes ----------------
// x:      (16, 3,16,128,128)
// y1:     (16, 4, 8, 64, 64)   conv1 k4 s2 p1 + relu
// y2:     (16, 8, 4, 32, 32)   conv2 k4 s2 p1 + relu
// z:      (16,16, 4, 32, 32)   conv4 k3 s1 p1 + clip(0,6)
// quant:  (16,16, 4, 32, 32)   VQ
// d1:     (16, 8, 8, 64, 64)   deconv1 k4 s2 p1 + relu  (padded: [10][66][72])
// d2:     (16, 4,16,128,128)   deconv3 k4 s2 p1 + relu  (padded: [18][130][136])
// out:    (16, 3,16,128,128)   deconv4 k3 s1 p1

// padded d2 geometry
#define P_STRIDE 136              // col = iw + 4; 16B-aligned rows
#define P_PLANE  (130 * P_STRIDE) // row = ih + 1
#define P_VOL    (18 * P_PLANE)   // plane = id + 1
// padded d1 geometry
#define D1_STRIDE 72              // col = iw + 4
#define D1_PLANE  (66 * D1_STRIDE)
#define D1_VOL    (10 * D1_PLANE)

__device__ __forceinline__ float4 ld4(const float* p) {
  return *reinterpret_cast<const float4*>(p);
}
__device__ __forceinline__ void st4(float* p, float4 v) {
  *reinterpret_cast<float4*>(p) = v;
}

// conv1 (R4 strip, measured fast): thread = 4 co x (1 od, 1 oh, 4 ow). 512 blocks.
__global__ __launch_bounds__(256) void conv1_k(
    const float* __restrict__ x, const float* __restrict__ w,
    const float* __restrict__ bias, float* __restrict__ y) {
  int idx = blockIdx.x * 256 + threadIdx.x;
  int g  = idx & 15;
  int oh = (idx >> 4) & 63;
  int od = (idx >> 10) & 7;
  int n  = idx >> 13;
  bool gl = (g > 0), gr = (g < 15);
  float acc[4][4];
  #pragma unroll
  for (int co = 0; co < 4; co++) {
    float bv = bias[co];
    #pragma unroll
    for (int m = 0; m < 4; m++) acc[co][m] = bv;
  }
  int ih0 = 2 * oh - 1;
  #pragma unroll 1
  for (int ci = 0; ci < 3; ci++) {
    #pragma unroll 1
    for (int kd = 0; kd < 4; kd++) {
      int id = 2 * od - 1 + kd;
      bool vd = (unsigned)id < 16u;
      int idc = vd ? id : 0;
      const float* plane = x + (((n * 3 + ci) * 16 + idc) * 16384);
      #pragma unroll
      for (int kh = 0; kh < 4; kh++) {
        int ih = ih0 + kh;
        bool v = vd && ((unsigned)ih < 128u);
        int ihc = (unsigned)ih < 128u ? ih : 0;
        const float* rp = plane + ihc * 128 + 8 * g;
        float r[10];
        float4 A = ld4(rp);
        float4 B = ld4(rp + 4);
        float rl = rp[-1 * (int)gl];
        float rr = rp[gr ? 8 : 0];
        r[0] = (v && gl) ? rl : 0.0f;
        r[1] = v ? A.x : 0.0f; r[2] = v ? A.y : 0.0f;
        r[3] = v ? A.z : 0.0f; r[4] = v ? A.w : 0.0f;
        r[5] = v ? B.x : 0.0f; r[6] = v ? B.y : 0.0f;
        r[7] = v ? B.z : 0.0f; r[8] = v ? B.w : 0.0f;
        r[9] = (v && gr) ? rr : 0.0f;
        #pragma unroll
        for (int co = 0; co < 4; co++) {
          const float* wb = w + ((co * 3 + ci) * 4 + kd) * 16 + kh * 4;
          #pragma unroll
          for (int kw = 0; kw < 4; kw++) {
            float wv = wb[kw];
            #pragma unroll
            for (int m = 0; m < 4; m++)
              acc[co][m] += r[2 * m + kw] * wv;
          }
        }
      }
    }
  }
  #pragma unroll
  for (int co = 0; co < 4; co++) {
    float4 o;
    o.x = fmaxf(acc[co][0], 0.0f); o.y = fmaxf(acc[co][1], 0.0f);
    o.z = fmaxf(acc[co][2], 0.0f); o.w = fmaxf(acc[co][3], 0.0f);
    st4(y + ((n * 4 + co) * 8 + od) * 4096 + oh * 64 + 4 * g, o);
  }
}

// conv2: thread = 1 pos x 4 co. 512 blocks.
__global__ __launch_bounds__(256) void conv2_k(
    const float* __restrict__ y1, const float* __restrict__ w,
    const float* __restrict__ bias, float* __restrict__ y) {
  int idx = blockIdx.x * 256 + threadIdx.x;
  int ow = idx & 31;
  int oh = (idx >> 5) & 31;
  int od = (idx >> 10) & 3;
  int n = (idx >> 12) & 15;
  int cog = idx >> 16;
  float acc[4];
  #pragma unroll
  for (int co = 0; co < 4; co++) acc[co] = bias[cog * 4 + co];
  int id0 = 2 * od - 1, ih0 = 2 * oh - 1, iw0 = 2 * ow - 1;
  bool vh[4], vw[4];
  #pragma unroll
  for (int l = 0; l < 4; l++) {
    vh[l] = (unsigned)(ih0 + l) < 64u;
    vw[l] = (unsigned)(iw0 + l) < 64u;
  }
  #pragma unroll 1
  for (int ci = 0; ci < 4; ci++) {
    const float* ip = y1 + ((n * 4 + ci) * 8) * 4096;
    #pragma unroll
    for (int kd = 0; kd < 4; kd++) {
      int id = id0 + kd;
      bool vd = (unsigned)id < 8u;
      const float* pp = ip + id * 4096;
      float p[4][4];
      #pragma unroll
      for (int kh = 0; kh < 4; kh++)
        #pragma unroll
        for (int kw = 0; kw < 4; kw++)
          p[kh][kw] = (vd && vh[kh] && vw[kw]) ? pp[(ih0 + kh) * 64 + (iw0 + kw)] : 0.0f;
      #pragma unroll
      for (int co = 0; co < 4; co++) {
        const float* wp = w + (((cog * 4 + co) * 4 + ci) * 4 + kd) * 16;
        #pragma unroll
        for (int kh = 0; kh < 4; kh++)
          #pragma unroll
          for (int kw = 0; kw < 4; kw++)
            acc[co] += p[kh][kw] * wp[kh * 4 + kw];
      }
    }
  }
  #pragma unroll
  for (int co = 0; co < 4; co++)
    y[((n * 8 + cog * 4 + co) * 4 + od) * 1024 + oh * 32 + ow] = fmaxf(acc[co], 0.0f);
}

// conv4: thread = 1 pos x 4 co. 1024 blocks.
__global__ __launch_bounds__(256) void conv4_k(
    const float* __restrict__ y2, const float* __restrict__ w,
    const float* __restrict__ bias, float* __restrict__ z) {
  int idx = blockIdx.x * 256 + threadIdx.x;
  int ow = idx & 31;
  int oh = (idx >> 5) & 31;
  int od = (idx >> 10) & 3;
  int n = (idx >> 12) & 15;
  int cog = idx >> 16;
  float acc[4];
  #pragma unroll
  for (int co = 0; co < 4; co++) acc[co] = bias[cog * 4 + co];
  bool vh[3], vw[3];
  #pragma unroll
  for (int l = 0; l < 3; l++) {
    vh[l] = (unsigned)(oh - 1 + l) < 32u;
    vw[l] = (unsigned)(ow - 1 + l) < 32u;
  }
  #pragma unroll 1
  for (int ci = 0; ci < 8; ci++) {
    const float* ip = y2 + ((n * 8 + ci) * 4) * 1024;
    #pragma unroll
    for (int kd = 0; kd < 3; kd++) {
      int id = od - 1 + kd;
      bool vd = (unsigned)id < 4u;
      const float* pp = ip + id * 1024;
      float p[3][3];
      #pragma unroll
      for (int kh = 0; kh < 3; kh++)
        #pragma unroll
        for (int kw = 0; kw < 3; kw++)
          p[kh][kw] = (vd && vh[kh] && vw[kw]) ? pp[(oh - 1 + kh) * 32 + (ow - 1 + kw)] : 0.0f;
      #pragma unroll
      for (int co = 0; co < 4; co++) {
        const float* wp = w + (((cog * 4 + co) * 8 + ci) * 3 + kd) * 9;
        #pragma unroll
        for (int kh = 0; kh < 3; kh++)
          #pragma unroll
          for (int kw = 0; kw < 3; kw++)
            acc[co] += p[kh][kw] * wp[kh * 3 + kw];
      }
    }
  }
  #pragma unroll
  for (int co = 0; co < 4; co++)
    z[((n * 16 + cog * 4 + co) * 4 + od) * 1024 + oh * 32 + ow] =
        fminf(fmaxf(acc[co], 0.0f), 6.0f);
}

// VQ (verified)
__global__ __launch_bounds__(256) void vq_k(
    const float* __restrict__ z, const float* __restrict__ emb,
    float* __restrict__ quant, float* __restrict__ codes_out,
    float* __restrict__ stats) {
  __shared__ float se[32 * 16];
  __shared__ float se2[32];
  __shared__ float shist[32];
  __shared__ float swred[4];
  int tid = threadIdx.x;
  for (int i = tid; i < 512; i += 256) {
    int r = i >> 4;
    float v = emb[i];
    if (r == 0) v = 0.0f;
    else if (r == 1) v = 6.0f;
    se[i] = v;
  }
  if (tid < 32) shist[tid] = 0.0f;
  __syncthreads();
  if (tid < 32) {
    float s = 0.0f;
    #pragma unroll
    for (int d = 0; d < 16; d++) { float v = se[tid * 16 + d]; s += v * v; }
    se2[tid] = s;
  }
  __syncthreads();

  int idx = blockIdx.x * 256 + tid;
  float lsum = 0.0f;
  {
    int w_ = idx & 31; int t = idx >> 5;
    int h_ = t & 31; t >>= 5;
    int d_ = t & 3;  int b_ = t >> 2;
    const float* zp = z + b_ * 65536 + d_ * 1024 + h_ * 32 + w_;
    float f[16];
    float f2 = 0.0f;
    #pragma unroll
    for (int c = 0; c < 16; c++) { float v = zp[c * 4096]; f[c] = v; f2 += v * v; }
    float best = 1e30f; int bi = 0;
    for (int e = 0; e < 32; e++) {
      float dot = 0.0f;
      #pragma unroll
      for (int c = 0; c < 16; c++) dot += f[c] * se[e * 16 + c];
      float d2 = f2 - 2.0f * dot + se2[e];
      if (d2 < best) { best = d2; bi = e; }
    }
    float* qp = quant + b_ * 65536 + d_ * 1024 + h_ * 32 + w_;
    #pragma unroll
    for (int c = 0; c < 16; c++) {
      float q = se[bi * 16 + c];
      qp[c * 4096] = q;
      float df = q - f[c];
      lsum += df * df;
    }
    codes_out[idx] = (float)bi;
    atomicAdd(&shist[bi], 1.0f);
  }
  for (int o = 32; o; o >>= 1) lsum += __shfl_down(lsum, o);
  if ((tid & 63) == 0) swred[tid >> 6] = lsum;
  __syncthreads();
  if (tid == 0) atomicAdd(&stats[0], swred[0] + swred[1] + swred[2] + swred[3]);
  if (tid < 32) {
    float h = shist[tid];
    if (h != 0.0f) atomicAdd(&stats[1 + tid], h);
  }
}

__global__ void init_stats_k(float* __restrict__ stats) {
  int tid = threadIdx.x;
  if (tid < 33) stats[tid] = 0.0f;
}

__global__ void fin_k(const float* __restrict__ stats,
                      const float* __restrict__ cluster_size,
                      float* __restrict__ out_loss, float* __restrict__ out_perp,
                      float* __restrict__ out_used) {
  int tid = threadIdx.x;
  float v = 0.0f;
  float used = 0.0f;
  if (tid < 32) {
    float p = stats[1 + tid] * (1.0f / 65536.0f);
    v = p * logf(p + 1e-10f);
    used = (cluster_size[tid] > 1e-5f) ? 1.0f : 0.0f;
  }
  for (int o = 16; o; o >>= 1) { v += __shfl_down(v, o); used += __shfl_down(used, o); }
  if (tid == 0) {
    *out_perp = expf(-v);
    *out_used = used * (1.0f / 32.0f);
    *out_loss = 0.25f * stats[0] * (1.0f / 1048576.0f);
  }
}

// ============ deconv1 strip — templated store target ============
template <int PADDED>
__global__ __launch_bounds__(256) void deconv1_t(
    const float* __restrict__ q, const float* __restrict__ w,
    const float* __restrict__ bias, float* __restrict__ d1) {
  int bid = blockIdx.x;
  int cog = bid & 1;
  int ph  = (bid >> 1) & 1;
  int od  = (bid >> 2) & 7;
  int n   = bid >> 5;
  int tid = threadIdx.x;
  int g   = tid & 7;
  int bl  = tid >> 3;
  bool glf = (g > 0), grf = (g < 7);

  int kd0 = (od + 1) & 1;
  int idtop = (od + 1 - kd0) >> 1;
  int kh0 = (ph + 1) & 1;
  int ihtop = bl + ph;

  float acc[4][8];
  #pragma unroll
  for (int co = 0; co < 4; co++) {
    float bv = bias[cog * 4 + co];
    #pragma unroll
    for (int m = 0; m < 8; m++) acc[co][m] = bv;
  }

  #pragma unroll 1
  for (int ci = 0; ci < 16; ci++) {
    const float* ip = q + ((n * 16 + ci) * 4) * 1024;
    #pragma unroll
    for (int jd = 0; jd < 2; jd++) {
      int id = idtop - jd;
      bool vd = (unsigned)id < 4u;
      int idc = vd ? id : 0;
      const float* plane = ip + idc * 1024;
      #pragma unroll
      for (int jh = 0; jh < 2; jh++) {
        int ih = ihtop - jh;
        bool v = vd && ((unsigned)ih < 32u);
        int ihc = (unsigned)ih < 32u ? ih : 0;
        const float* rp = plane + ihc * 32 + 4 * g;
        float r[6];
        float4 A = ld4(rp);
        float rl = rp[-1 * (int)glf];
        float rr = rp[grf ? 4 : 0];
        r[0] = (v && glf) ? rl : 0.0f;
        r[1] = v ? A.x : 0.0f; r[2] = v ? A.y : 0.0f;
        r[3] = v ? A.z : 0.0f; r[4] = v ? A.w : 0.0f;
        r[5] = (v && grf) ? rr : 0.0f;
        int kd = kd0 + 2 * jd;
        int kh = kh0 + 2 * jh;
        #pragma unroll
        for (int co = 0; co < 4; co++) {
          const float* wb = w + ((ci * 8 + cog * 4 + co) * 4 + kd) * 16 + kh * 4;
          #pragma unroll
          for (int jw = 0; jw < 2; jw++) {
            float w_ev = wb[1 + 2 * jw];
            float w_od = wb[2 * jw];
            #pragma unroll
            for (int ii = 0; ii < 4; ii++) {
              acc[co][2 * ii]     += r[ii + 1 - jw] * w_ev;
              acc[co][2 * ii + 1] += r[ii + 2 - jw] * w_od;
            }
          }
        }
      }
    }
  }
  int oh = 2 * bl + ph;
  #pragma unroll
  for (int co = 0; co < 4; co++) {
    float* op;
    if (PADDED)
      op = d1 + (size_t)(n * 8 + cog * 4 + co) * D1_VOL +
           (od + 1) * D1_PLANE + (oh + 1) * D1_STRIDE + 8 * g + 4;
    else
      op = d1 + ((n * 8 + cog * 4 + co) * 8 + od) * 4096 + oh * 64 + 8 * g;
    float4 lo, hi;
    lo.x = fmaxf(acc[co][0], 0.0f); lo.y = fmaxf(acc[co][1], 0.0f);
    lo.z = fmaxf(acc[co][2], 0.0f); lo.w = fmaxf(acc[co][3], 0.0f);
    hi.x = fmaxf(acc[co][4], 0.0f); hi.y = fmaxf(acc[co][5], 0.0f);
    hi.z = fmaxf(acc[co][6], 0.0f); hi.w = fmaxf(acc[co][7], 0.0f);
    st4(op, lo); st4(op + 4, hi);
  }
}

// ============ deconv3 strip — templated input (d1) and output (d2) ============
template <int INP, int OUTP>
__global__ __launch_bounds__(256) void deconv3_t(
    const float* __restrict__ d1, const float* __restrict__ w,
    const float* __restrict__ bias, float* __restrict__ d2) {
  int bid = blockIdx.x;
  int ph  = bid & 1;
  int blh = (bid >> 1) & 3;
  int od  = (bid >> 3) & 15;
  int n   = bid >> 7;
  int tid = threadIdx.x;
  int g   = tid & 15;
  int bl  = tid >> 4;
  int BL  = blh * 16 + bl;
  bool glf = (g > 0), grf = (g < 15);

  int kd0 = (od + 1) & 1;
  int idtop = (od + 1 - kd0) >> 1;
  int kh0 = (ph + 1) & 1;
  int ihtop = BL + ph;

  float acc[4][8];
  #pragma unroll
  for (int co = 0; co < 4; co++) {
    float bv = bias[co];
    #pragma unroll
    for (int m = 0; m < 8; m++) acc[co][m] = bv;
  }

  #pragma unroll 1
  for (int ci = 0; ci < 8; ci++) {
    #pragma unroll
    for (int jd = 0; jd < 2; jd++) {
      #pragma unroll
      for (int jh = 0; jh < 2; jh++) {
        float r[6];
        if (INP) {
          const float* rp = d1 + (size_t)(n * 8 + ci) * D1_VOL +
                            (idtop + 1 - jd) * D1_PLANE + (ihtop + 1 - jh) * D1_STRIDE +
                            4 * g + 4;
          float4 A = ld4(rp);
          r[0] = rp[-1];
          r[1] = A.x; r[2] = A.y; r[3] = A.z; r[4] = A.w;
          r[5] = rp[4];
        } else {
          const float* ip = d1 + ((n * 8 + ci) * 8) * 4096;
          int id = idtop - jd;
          bool vd = (unsigned)id < 8u;
          int idc = vd ? id : 0;
          const float* plane = ip + idc * 4096;
          int ih = ihtop - jh;
          bool v = vd && ((unsigned)ih < 64u);
          int ihc = (unsigned)ih < 64u ? ih : 0;
          const float* rp = plane + ihc * 64 + 4 * g;
          float4 A = ld4(rp);
          float rl = rp[-1 * (int)glf];
          float rr = rp[grf ? 4 : 0];
          r[0] = (v && glf) ? rl : 0.0f;
          r[1] = v ? A.x : 0.0f; r[2] = v ? A.y : 0.0f;
          r[3] = v ? A.z : 0.0f; r[4] = v ? A.w : 0.0f;
          r[5] = (v && grf) ? rr : 0.0f;
        }
        int kd = kd0 + 2 * jd;
        int kh = kh0 + 2 * jh;
        #pragma unroll
        for (int co = 0; co < 4; co++) {
          const float* wb = w + ((ci * 4 + co) * 4 + kd) * 16 + kh * 4;
          #pragma unroll
          for (int jw = 0; jw < 2; jw++) {
            float w_ev = wb[1 + 2 * jw];
            float w_od = wb[2 * jw];
            #pragma unroll
            for (int ii = 0; ii < 4; ii++) {
              acc[co][2 * ii]     += r[ii + 1 - jw] * w_ev;
              acc[co][2 * ii + 1] += r[ii + 2 - jw] * w_od;
            }
          }
        }
      }
    }
  }
  int oh = 2 * BL + ph;
  #pragma unroll
  for (int co = 0; co < 4; co++) {
    float* op;
    if (OUTP)
      op = d2 + (size_t)(n * 4 + co) * P_VOL + (od + 1) * P_PLANE + (oh + 1) * P_STRIDE + 8 * g + 4;
    else
      op = d2 + ((n * 4 + co) * 16 + od) * 16384 + oh * 128 + 8 * g;
    float4 lo, hi;
    lo.x = fmaxf(acc[co][0], 0.0f); lo.y = fmaxf(acc[co][1], 0.0f);
    lo.z = fmaxf(acc[co][2], 0.0f); lo.w = fmaxf(acc[co][3], 0.0f);
    hi.x = fmaxf(acc[co][4], 0.0f); hi.y = fmaxf(acc[co][5], 0.0f);
    hi.z = fmaxf(acc[co][6], 0.0f); hi.w = fmaxf(acc[co][7], 0.0f);
    st4(op, lo); st4(op + 4, hi);
  }
}

// zero the read-but-never-written halo of d2p
__global__ __launch_bounds__(256) void zero_halo_k(float* __restrict__ d2p) {
  const int PER = 43808;
  int total = PER * 64;
  for (int i = blockIdx.x * 256 + threadIdx.x; i < total; i += gridDim.x * 256) {
    int nc = i / PER;
    int j = i - nc * PER;
    int elem;
    if (j < 35360) {
      int pd = (j < 17680) ? 0 : 17;
      int off = (j < 17680) ? j : j - 17680;
      elem = pd * P_PLANE + off;
    } else if (j < 39712) {
      int k = j - 35360;
      int pd = 1 + (k / 272);
      int rj = k - (pd - 1) * 272;
      int row = (rj < 136) ? 0 : 129;
      int col = (rj < 136) ? rj : rj - 136;
      elem = pd * P_PLANE + row * P_STRIDE + col;
    } else {
      int k = j - 39712;
      int pd = 1 + (k / 256);
      int rj = k - (pd - 1) * 256;
      int row = 1 + (rj >> 1);
      int col = (rj & 1) ? 132 : 3;
      elem = pd * P_PLANE + row * P_STRIDE + col;
    }
    d2p[(size_t)nc * P_VOL + elem] = 0.0f;
  }
}

// zero the read-but-never-written halo of d1p
__global__ __launch_bounds__(256) void zero_halo_d1p_k(float* __restrict__ d1p) {
  const int PER = 11680;
  int total = PER * 128;
  for (int i = blockIdx.x * 256 + threadIdx.x; i < total; i += gridDim.x * 256) {
    int nc = i / PER;
    int j = i - nc * PER;
    int elem;
    if (j < 9504) {
      int pd = (j < 4752) ? 0 : 9;
      int off = (j < 4752) ? j : j - 4752;
      elem = pd * D1_PLANE + off;
    } else if (j < 10656) {
      int k = j - 9504;
      int pd = 1 + (k / 144);
      int rj = k - (pd - 1) * 144;
      int row = (rj < 72) ? 0 : 65;
      int col = (rj < 72) ? rj : rj - 72;
      elem = pd * D1_PLANE + row * D1_STRIDE + col;
    } else {
      int k = j - 10656;
      int pd = 1 + (k / 128);
      int rj = k - (pd - 1) * 128;
      int row = 1 + (rj >> 1);
      int col = (rj & 1) ? 68 : 3;
      elem = pd * D1_PLANE + row * D1_STRIDE + col;
    }
    d1p[(size_t)nc * D1_VOL + elem] = 0.0f;
  }
}

// ============ deconv4 cube, legacy (verified 78.6us, tier-C fallback) ============
__global__ __launch_bounds__(256) void deconv4_k(
    const float* __restrict__ d2, const float* __restrict__ w,
    const float* __restrict__ bias, float* __restrict__ out) {
  int idx = blockIdx.x * 256 + threadIdx.x;
  int c = idx & 63;
  int b = (idx >> 6) & 63;
  int a = (idx >> 12) & 7;
  int n = idx >> 15;
  float acc[2][2][2][3];
  #pragma unroll
  for (int pd = 0; pd < 2; pd++)
    #pragma unroll
    for (int ph = 0; ph < 2; ph++)
      #pragma unroll
      for (int pw = 0; pw < 2; pw++)
        #pragma unroll
        for (int co = 0; co < 3; co++) acc[pd][ph][pw][co] = bias[co];
  int ih0 = 2 * b - 1, iw0 = 2 * c - 1;
  bool vh[4], vw[4];
  #pragma unroll
  for (int l = 0; l < 4; l++) {
    vh[l] = (unsigned)(ih0 + l) < 128u;
    vw[l] = (unsigned)(iw0 + l) < 128u;
  }
  #pragma unroll 1
  for (int ci = 0; ci < 4; ci++) {
    const float* ip = d2 + ((n * 4 + ci) * 16) * 16384;
    #pragma unroll
    for (int ld = 0; ld < 4; ld++) {
      int id = 2 * a - 1 + ld;
      bool vdl = (unsigned)id < 16u;
      const float* pp = ip + id * 16384;
      float p[4][4];
      #pragma unroll
      for (int lh = 0; lh < 4; lh++)
        #pragma unroll
        for (int lw = 0; lw < 4; lw++)
          p[lh][lw] = (vdl && vh[lh] && vw[lw]) ? pp[(ih0 + lh) * 128 + (iw0 + lw)] : 0.0f;
      #pragma unroll
      for (int pd = 0; pd < 2; pd++) {
        int kd = pd + 2 - ld;
        if (kd < 0 || kd > 2) continue;
        #pragma unroll
        for (int kh = 0; kh < 3; kh++)
          #pragma unroll
          for (int kw = 0; kw < 3; kw++)
            #pragma unroll
            for (int co = 0; co < 3; co++) {
              float wv = w[(ci * 3 + co) * 27 + kd * 9 + kh * 3 + kw];
              #pragma unroll
              for (int ph = 0; ph < 2; ph++)
                #pragma unroll
                for (int pw = 0; pw < 2; pw++)
                  acc[pd][ph][pw][co] += p[ph + 2 - kh][pw + 2 - kw] * wv;
            }
      }
    }
  }
  #pragma unroll
  for (int co = 0; co < 3; co++)
    #pragma unroll
    for (int pd = 0; pd < 2; pd++)
      #pragma unroll
      for (int ph = 0; ph < 2; ph++)
        #pragma unroll
        for (int pw = 0; pw < 2; pw++)
          out[((n * 3 + co) * 16 + 2 * a + pd) * 16384 +
              (2 * b + ph) * 128 + (2 * c + pw)] = acc[pd][ph][pw][co];
}

// ============ deconv4 wide cube, padded input ============
// Thread = 2(d) x 2(h) x 4(w) x 3 co; unconditional loads (halo pre-zeroed);
// per row the used window cols 4c+3..4c+8 -> dword+dwordx4+dword, coalesced.
// 1024 blocks x 256. Index algebra identical to verified cube with iw0=4c-1:
// tap = pr[ph+2-kh][(pw+2-kw)+3], kd = pd+2-ld.
__global__ __launch_bounds__(256) void deconv4p_k(
    const float* __restrict__ d2p, const float* __restrict__ w,
    const float* __restrict__ bias, float* __restrict__ out) {
  int idx = blockIdx.x * 256 + threadIdx.x;
  int c = idx & 31;          // ow base 4c
  int b = (idx >> 5) & 63;   // oh base 2b
  int a = (idx >> 11) & 7;   // od base 2a
  int n = idx >> 14;
  float acc[2][2][3][4];     // [pd][ph][co][pw]
  #pragma unroll
  for (int pd = 0; pd < 2; pd++)
    #pragma unroll
    for (int ph = 0; ph < 2; ph++)
      #pragma unroll
      for (int co = 0; co < 3; co++) {
        float bv = bias[co];
        #pragma unroll
        for (int pw = 0; pw < 4; pw++) acc[pd][ph][co][pw] = bv;
      }
  #pragma unroll 1
  for (int ci = 0; ci < 4; ci++) {
    // base at (plane 2a, row 2b, col 4c): window cols 4c+3..4c+8 within 0..11
    const float* ip = d2p + (size_t)(n * 4 + ci) * P_VOL +
                      (2 * a) * P_PLANE + (2 * b) * P_STRIDE + (4 * c);
    #pragma unroll
    for (int ld = 0; ld < 4; ld++) {
      const float* pp = ip + ld * P_PLANE;
      float pr[4][12];
      #pragma unroll
      for (int lh = 0; lh < 4; lh++) {
        const float* rp = pp + lh * P_STRIDE;
        float4 A = ld4(rp);
        float4 B = ld4(rp + 4);
        float4 C = ld4(rp + 8);
        pr[lh][0] = A.x;  pr[lh][1] = A.y;  pr[lh][2] = A.z;  pr[lh][3] = A.w;
        pr[lh][4] = B.x;  pr[lh][5] = B.y;  pr[lh][6] = B.z;  pr[lh][7] = B.w;
        pr[lh][8] = C.x;  pr[lh][9] = C.y;  pr[lh][10] = C.z; pr[lh][11] = C.w;
      }
      #pragma unroll
      for (int pd = 0; pd < 2; pd++) {
        int kd = pd + 2 - ld;
        if (kd < 0 || kd > 2) continue;
        #pragma unroll
        for (int kh = 0; kh < 3; kh++)
          #pragma unroll
          for (int kw = 0; kw < 3; kw++)
            #pragma unroll
            for (int co = 0; co < 3; co++) {
              float wv = w[(ci * 3 + co) * 27 + kd * 9 + kh * 3 + kw];
              #pragma unroll
              for (int ph = 0; ph < 2; ph++)
                #pragma unroll
                for (int pw = 0; pw < 4; pw++)
                  acc[pd][ph][co][pw] += pr[ph + 2 - kh][pw + 5 - kw] * wv;
            }
      }
    }
  }
  #pragma unroll
  for (int co = 0; co < 3; co++)
    #pragma unroll
    for (int pd = 0; pd < 2; pd++)
      #pragma unroll
      for (int ph = 0; ph < 2; ph++) {
        float4 o;
        o.x = acc[pd][ph][co][0]; o.y = acc[pd][ph][co][1];
        o.z = acc[pd][ph][co][2]; o.w = acc[pd][ph][co][3];
        st4(out + ((n * 3 + co) * 16 + 2 * a + pd) * 16384 +
            (2 * b + ph) * 128 + 4 * c, o);
      }
}

extern "C" void kernel_launch(void* const* d_in, const int* in_sizes, int n_in,
                              void* d_out, int out_size, void* d_ws, size_t ws_size,
                              hipStream_t stream) {
  const float* x      = (const float*)d_in[0];
  const float* enc_w1 = (const float*)d_in[2];
  const float* enc_b1 = (const float*)d_in[3];
  const float* enc_w2 = (const float*)d_in[4];
  const float* enc_b2 = (const float*)d_in[5];
  const float* enc_w4 = (const float*)d_in[6];
  const float* enc_b4 = (const float*)d_in[7];
  const float* dec_w1 = (const float*)d_in[8];
  const float* dec_b1 = (const float*)d_in[9];
  const float* dec_w3 = (const float*)d_in[10];
  const float* dec_b3 = (const float*)d_in[11];
  const float* dec_w4 = (const float*)d_in[12];
  const float* dec_b4 = (const float*)d_in[13];
  const float* emb    = (const float*)d_in[14];
  const float* csize  = (const float*)d_in[15];

  float* ws = (float*)d_ws;
  float* stats = ws;                      // 64
  float* quant = ws + 64;                 // 1,048,576
  float* z     = quant + 1048576;         // 1,048,576
  float* y2    = z + 1048576;             // 524,288
  float* y1    = y2 + 524288;             // 2,097,152 (dead after conv2)

  float* out   = (float*)d_out;                        // 12,582,912
  float* out_loss  = out + 12582912;
  float* out_codes = out_loss + 1;                     // 65,536
  float* out_perp  = out_codes + 65536;
  float* out_used  = out_perp + 1;

  // Tier A (full pad): d1p (6,082,560) + d2p (20,367,360)
  const size_t FULL_NEED = (size_t)(64 + 1048576 + 6082560 + 20367360) * sizeof(float);
  // Tier B: legacy d1 (4,194,304) + d2p
  const size_t MID_NEED  = (size_t)(64 + 1048576 + 4194304 + 20367360) * sizeof(float);

  init_stats_k<<<1, 64, 0, stream>>>(stats);

  conv1_k<<<512, 256, 0, stream>>>(x, enc_w1, enc_b1, y1);
  conv2_k<<<512, 256, 0, stream>>>(y1, enc_w2, enc_b2, y2);
  conv4_k<<<1024, 256, 0, stream>>>(y2, enc_w4, enc_b4, z);

  vq_k<<<256, 256, 0, stream>>>(z, emb, quant, out_codes, stats);
  fin_k<<<1, 64, 0, stream>>>(stats, csize, out_loss, out_perp, out_used);

  if (ws_size >= FULL_NEED) {
    float* d1p = ws + 64 + 1048576;                  // overlaps dead z/y2/y1
    float* d2p = d1p + 6082560;
    zero_halo_k<<<1024, 256, 0, stream>>>(d2p);
    zero_halo_d1p_k<<<1024, 256, 0, stream>>>(d1p);  // after vq_k: z now dead
    deconv1_t<1><<<512, 256, 0, stream>>>(quant, dec_w1, dec_b1, d1p);
    deconv3_t<1, 1><<<2048, 256, 0, stream>>>(d1p, dec_w3, dec_b3, d2p);
    deconv4p_k<<<1024, 256, 0, stream>>>(d2p, dec_w4, dec_b4, out);
  } else if (ws_size >= MID_NEED) {
    float* d1  = ws + 64 + 1048576;
    float* d2p = d1 + 4194304;
    zero_halo_k<<<1024, 256, 0, stream>>>(d2p);
    deconv1_t<0><<<512, 256, 0, stream>>>(quant, dec_w1, dec_b1, d1);
    deconv3_t<0, 1><<<2048, 256, 0, stream>>>(d1, dec_w3, dec_b3, d2p);
    deconv4p_k<<<1024, 256, 0, stream>>>(d2p, dec_w4, dec_b4, out);
  } else {
    float* d1 = ws + 64 + 1048576;
    float* d2 = d1 + 4194304;
    deconv1_t<0><<<512, 256, 0, stream>>>(quant, dec_w1, dec_b1, d1);
    deconv3_t<0, 0><<<2048, 256, 0, stream>>>(d1, dec_w3, dec_b3, d2);
    deconv4_k<<<2048, 256, 0, stream>>>(d2, dec_w4, dec_b4, out);
  }
}